// Round 11
// baseline (184.842 us; speedup 1.0000x reference)
//
#include <hip/hip_runtime.h>

#define N_NODES 100000
#define D_FEAT  64
#define N_EDGES 3200000
#define GAMMA   0.5f

#define BSH   8                                   // 256 nodes per bucket
#define BN    (1 << BSH)                          // 256
#define NB    ((N_NODES + BN - 1) >> BSH)         // 391 buckets
#define NBP   512                                 // pow2 pad for scans

#define H_BLOCKS 1000
#define H_EPB    3200                             // edges per hist block (800 int4)

#define CVT_V4     (N_NODES * D_FEAT / 4)         // 1,600,000 float4
#define CVT_BLOCKS ((CVT_V4 + 255) / 256)         // 6250

#define K1_CH    4096                             // edges per K1 block
#define K1_BLOCKS ((N_EDGES + K1_CH - 1) / K1_CH) // 782

#define K2_CAP   10240                            // max recs sortable in LDS

#define SRC_MASK 0x1FFFFu                         // 17 bits for src

// ---- P0: fused [dst-bucket histogram (int4) + zero edge-out] | [h f32->bf16] ----
__global__ void pre_kernel(const float* __restrict__ h,
                           const int* __restrict__ dst,
                           unsigned short* __restrict__ h16,
                           int* __restrict__ counts,
                           float* __restrict__ out_edge) {
    __shared__ int lcnt[NB];
    const int bid = blockIdx.x;
    if (bid < H_BLOCKS) {
        for (int i = threadIdx.x; i < NB; i += 256) lcnt[i] = 0;
        __syncthreads();
        const int4*  dst4 = (const int4*)(dst + bid * H_EPB);
        float4*      oe4  = (float4*)(out_edge + bid * H_EPB);
        const float4 z4   = make_float4(0.f, 0.f, 0.f, 0.f);
        for (int i = threadIdx.x; i < H_EPB / 4; i += 256) {
            int4 d = dst4[i];
            __hip_atomic_fetch_add(&lcnt[d.x >> BSH], 1, __ATOMIC_RELAXED, __HIP_MEMORY_SCOPE_WORKGROUP);
            __hip_atomic_fetch_add(&lcnt[d.y >> BSH], 1, __ATOMIC_RELAXED, __HIP_MEMORY_SCOPE_WORKGROUP);
            __hip_atomic_fetch_add(&lcnt[d.z >> BSH], 1, __ATOMIC_RELAXED, __HIP_MEMORY_SCOPE_WORKGROUP);
            __hip_atomic_fetch_add(&lcnt[d.w >> BSH], 1, __ATOMIC_RELAXED, __HIP_MEMORY_SCOPE_WORKGROUP);
            oe4[i] = z4;
        }
        __syncthreads();
        for (int i = threadIdx.x; i < NB; i += 256) {
            int c = lcnt[i];
            if (c) atomicAdd(&counts[i], c);
        }
    } else {
        int i = (bid - H_BLOCKS) * 256 + threadIdx.x;
        if (i < CVT_V4) {
            float4 v = ((const float4*)h)[i];
            ushort4 o;
            unsigned u;
            u = __float_as_uint(v.x); o.x = (unsigned short)((u + 0x7fffu + ((u >> 16) & 1u)) >> 16);
            u = __float_as_uint(v.y); o.y = (unsigned short)((u + 0x7fffu + ((u >> 16) & 1u)) >> 16);
            u = __float_as_uint(v.z); o.z = (unsigned short)((u + 0x7fffu + ((u >> 16) & 1u)) >> 16);
            u = __float_as_uint(v.w); o.w = (unsigned short)((u + 0x7fffu + ((u >> 16) & 1u)) >> 16);
            ((ushort4*)h16)[i] = o;
        }
    }
}

// ---- P1: scan 391 bucket counts -> offs/curs; init bflag, node_offs tail ----
__global__ void scan_kernel(const int* __restrict__ counts,
                            int* __restrict__ offs,
                            int* __restrict__ curs,
                            int* __restrict__ bflag,
                            int* __restrict__ node_offs) {
    __shared__ int sb[NBP];
    int t = threadIdx.x;
    int c = (t < NB) ? counts[t] : 0;
    sb[t] = c;
    __syncthreads();
    for (int off = 1; off < NBP; off <<= 1) {
        int v = 0;
        if (t >= off) v = sb[t - off];
        __syncthreads();
        sb[t] += v;
        __syncthreads();
    }
    if (t < NB) {
        offs[t] = sb[t] - c;
        curs[t] = sb[t] - c;
        bflag[t] = 0;
    }
    if (t == NBP - 1) offs[NB] = sb[t];
    if (t == 0) node_offs[N_NODES] = N_EDGES;
}

// ---- K1: direct bucket scatter. Per-block LDS histogram -> one global
// reservation per (block,bucket) -> direct rec writes at LDS cursors.
// Writes cluster in ~10-rec windows near 391 block-private heads: L2 merges.
__global__ void __launch_bounds__(512)
bucket_scatter_kernel(const int* __restrict__ src,
                      const int* __restrict__ dst,
                      const float* __restrict__ e,
                      int* __restrict__ curs,
                      uint2* __restrict__ recs) {
    __shared__ int hist[NB], cur[NB], gbase[NB];  // 4.7 KB

    const int t    = threadIdx.x;
    const int base = blockIdx.x * K1_CH;
    int chcnt = N_EDGES - base; if (chcnt > K1_CH) chcnt = K1_CH;

    int dv[8];                                    // register-cached dst
    for (int i = t; i < NB; i += 512) hist[i] = 0;
    __syncthreads();
#pragma unroll
    for (int j = 0; j < 8; ++j) {
        int i = j * 512 + t;
        if (i < chcnt) {
            dv[j] = dst[base + i];
            __hip_atomic_fetch_add(&hist[dv[j] >> BSH], 1,
                                   __ATOMIC_RELAXED, __HIP_MEMORY_SCOPE_WORKGROUP);
        } else dv[j] = -1;
    }
    __syncthreads();
    for (int i = t; i < NB; i += 512) {
        cur[i] = 0;
        int c = hist[i];
        gbase[i] = c ? atomicAdd(&curs[i], c) : 0;   // reserve once per bucket
    }
    __syncthreads();
#pragma unroll
    for (int j = 0; j < 8; ++j) {
        if (dv[j] >= 0) {
            int gi = base + j * 512 + t;
            int b  = dv[j] >> BSH;
            int p  = gbase[b] + __hip_atomic_fetch_add(&cur[b], 1,
                            __ATOMIC_RELAXED, __HIP_MEMORY_SCOPE_WORKGROUP);
            unsigned pk = (unsigned)src[gi] | ((unsigned)(dv[j] & (BN - 1)) << 17);
            recs[p] = make_uint2(pk, __float_as_uint(e[gi]));
        }
    }
}

// ---- K2: per-bucket node-level sort (in LDS, in place) + node_offs ----
// wave-shfl two-level scan (2 barriers instead of 16)
__global__ void __launch_bounds__(512)
node_sort_kernel(const int* __restrict__ offs,
                 uint2* __restrict__ recs,
                 int* __restrict__ bflag,
                 int* __restrict__ node_offs) {
    __shared__ uint2 buf[K2_CAP];                 // 80 KB
    __shared__ int hist[BN], ebuf[BN], cur[BN];
    __shared__ int wsum[4];

    const int b    = blockIdx.x;
    const int t    = threadIdx.x;
    const int lane = t & 63;
    const int wid  = t >> 6;
    const int lo   = offs[b];
    const int cnt  = offs[b + 1] - lo;

    if (cnt > K2_CAP) {                           // overflow fallback (rare)
        if (t == 0) bflag[b] = 1;
        if (t < BN) {
            int g = (b << BSH) + t;
            if (g < N_NODES) node_offs[g] = lo;
        }
        return;
    }

    if (t < BN) hist[t] = 0;
    __syncthreads();
    for (int i = t; i < cnt; i += 512) {
        uint2 r = recs[lo + i];
        buf[i] = r;
        __hip_atomic_fetch_add(&hist[r.x >> 17], 1,
                               __ATOMIC_RELAXED, __HIP_MEMORY_SCOPE_WORKGROUP);
    }
    __syncthreads();
    // two-level scan over 256 bins: wave shfl inclusive + cross-wave prefix
    int c = 0, incl = 0;
    if (t < BN) { c = hist[t]; incl = c; }
    for (int s = 1; s < 64; s <<= 1) {
        int u = __shfl_up(incl, s, 64);
        if (lane >= s) incl += u;
    }
    if (t < BN && lane == 63) wsum[wid] = incl;
    __syncthreads();
    if (t < BN) {
        int pre = 0;
        for (int w = 0; w < wid; ++w) pre += wsum[w];
        int exc = pre + incl - c;
        ebuf[t] = exc;
        cur[t]  = 0;
        int g = (b << BSH) + t;
        if (g < N_NODES) node_offs[g] = lo + exc;
    }
    __syncthreads();
    for (int i = t; i < cnt; i += 512) {
        uint2 r = buf[i];
        int dl = r.x >> 17;
        int p  = lo + ebuf[dl] + __hip_atomic_fetch_add(&cur[dl], 1,
                        __ATOMIC_RELAXED, __HIP_MEMORY_SCOPE_WORKGROUP);
        recs[p] = r;
    }
}

// ---- K3 (bf16 h): wave = node; 8 groups x 8 lanes; uint4 row loads ----
__global__ void __launch_bounds__(512)
gather_bf16_kernel(const float* __restrict__ h,
                   const unsigned short* __restrict__ h16,
                   const int* __restrict__ offs,
                   const int* __restrict__ node_offs,
                   const int* __restrict__ bflag,
                   const uint2* __restrict__ recs,
                   float* __restrict__ out) {
    const int wid = threadIdx.x >> 6;
    const int n   = blockIdx.x * 8 + wid;
    if (n >= N_NODES) return;
    const int lane = threadIdx.x & 63;
    const int g    = lane >> 3;        // 0..7
    const int sub  = lane & 7;         // 0..7
    const int b    = n >> BSH;

    const uint4* __restrict__ hv = (const uint4*)h16;   // 8 uint4 per row

    float a0=0.f,a1=0.f,a2=0.f,a3=0.f,a4=0.f,a5=0.f,a6=0.f,a7=0.f;

#define ACC_REC(r)                                                          \
    {                                                                       \
        uint4 v = hv[(r.x & SRC_MASK) * 8 + sub];                           \
        float w = __uint_as_float(r.y);                                     \
        a0 += __uint_as_float(v.x << 16) * w;                               \
        a1 += __uint_as_float(v.x & 0xFFFF0000u) * w;                       \
        a2 += __uint_as_float(v.y << 16) * w;                               \
        a3 += __uint_as_float(v.y & 0xFFFF0000u) * w;                       \
        a4 += __uint_as_float(v.z << 16) * w;                               \
        a5 += __uint_as_float(v.z & 0xFFFF0000u) * w;                       \
        a6 += __uint_as_float(v.w << 16) * w;                               \
        a7 += __uint_as_float(v.w & 0xFFFF0000u) * w;                       \
    }

    if (!bflag[b]) {
        const int lo = node_offs[n], hi = node_offs[n + 1];
        int kk = lo + g;
        while (kk < hi) {
            uint2 r0 = recs[kk];
            uint2 r1 = (kk +  8 < hi) ? recs[kk +  8] : make_uint2(0u, 0u);
            uint2 r2 = (kk + 16 < hi) ? recs[kk + 16] : make_uint2(0u, 0u);
            uint2 r3 = (kk + 24 < hi) ? recs[kk + 24] : make_uint2(0u, 0u);
            ACC_REC(r0); ACC_REC(r1); ACC_REC(r2); ACC_REC(r3);
            kk += 32;
        }
    } else {                                      // unsorted bucket: scan-match
        const int lo = offs[b], hi = offs[b + 1];
        const unsigned dl = (unsigned)(n & (BN - 1));
        for (int k = lo + g; k < hi; k += 8) {
            uint2 r = recs[k];
            if ((r.x >> 17) == dl) ACC_REC(r);
        }
    }
#undef ACC_REC

    for (int m = 8; m <= 32; m <<= 1) {
        a0 += __shfl_xor(a0, m); a1 += __shfl_xor(a1, m);
        a2 += __shfl_xor(a2, m); a3 += __shfl_xor(a3, m);
        a4 += __shfl_xor(a4, m); a5 += __shfl_xor(a5, m);
        a6 += __shfl_xor(a6, m); a7 += __shfl_xor(a7, m);
    }

    if (g == 0) {
        const float4* __restrict__ h4 = (const float4*)h;
        const int o = n * 16 + sub * 2;
        float4 p = h4[o], q = h4[o + 1];
        float4 r0, r1;
        r0.x = a0 - GAMMA * p.x; r0.y = a1 - GAMMA * p.y;
        r0.z = a2 - GAMMA * p.z; r0.w = a3 - GAMMA * p.w;
        r1.x = a4 - GAMMA * q.x; r1.y = a5 - GAMMA * q.y;
        r1.z = a6 - GAMMA * q.z; r1.w = a7 - GAMMA * q.w;
        ((float4*)out)[o]     = r0;
        ((float4*)out)[o + 1] = r1;
    }
}

// ---------------- fallback atomic path (if ws too small) ----------------
__global__ void init_out_kernel(const float* __restrict__ x,
                                float* __restrict__ out,
                                int nd, int total) {
    int i = blockIdx.x * blockDim.x + threadIdx.x;
    if (i < nd)         out[i] = -GAMMA * x[i];
    else if (i < total) out[i] = 0.0f;
}

__global__ void edge_scatter_kernel(const float* __restrict__ h,
                                    const float* __restrict__ e,
                                    const int* __restrict__ src,
                                    const int* __restrict__ dst,
                                    float* __restrict__ out) {
    long long idx = (long long)blockIdx.x * blockDim.x + threadIdx.x;
    int edge = (int)(idx >> 6);
    int d    = (int)(idx & 63);
    if (edge >= N_EDGES) return;
    atomicAdd(&out[dst[edge] * D_FEAT + d], h[src[edge] * D_FEAT + d] * e[edge]);
}

// ---------------- launch ----------------
extern "C" void kernel_launch(void* const* d_in, const int* in_sizes, int n_in,
                              void* d_out, int out_size, void* d_ws, size_t ws_size,
                              hipStream_t stream) {
    const float* x   = (const float*)d_in[1];
    const int*   src = (const int*)d_in[2];
    const int*   dst = (const int*)d_in[3];
    float*       out = (float*)d_out;

    const int nd = N_NODES * D_FEAT;

    // ws: counts[NB] | offs[NB+1] | curs[NB] | bflag[NB] | node_offs[N+1] |
    //     pad->256B | recs[E] (uint2) | pad->256B | h16[nd]   (layout frozen from R10)
    size_t ints    = (size_t)NB * 4 + 1 + (size_t)N_NODES + 1;
    size_t rec_off = (ints * 4 + 255) & ~(size_t)255;
    size_t h16_off = (rec_off + (size_t)N_EDGES * 8 + 255) & ~(size_t)255;
    size_t needed  = h16_off + (size_t)nd * 2;

    if (ws_size >= needed) {
        int*   counts    = (int*)d_ws;
        int*   offs      = counts + NB;
        int*   curs      = offs + NB + 1;
        int*   bflag     = curs + NB;
        int*   node_offs = bflag + NB;
        uint2* recs      = (uint2*)((char*)d_ws + rec_off);
        unsigned short* h16 = (unsigned short*)((char*)d_ws + h16_off);

        hipMemsetAsync(counts, 0, NB * sizeof(int), stream);
        pre_kernel<<<H_BLOCKS + CVT_BLOCKS, 256, 0, stream>>>(x, dst, h16, counts, out + nd);
        scan_kernel<<<1, NBP, 0, stream>>>(counts, offs, curs, bflag, node_offs);
        bucket_scatter_kernel<<<K1_BLOCKS, 512, 0, stream>>>(src, dst, x + nd, curs, recs);
        node_sort_kernel<<<NB, 512, 0, stream>>>(offs, recs, bflag, node_offs);
        gather_bf16_kernel<<<(N_NODES + 7) / 8, 512, 0, stream>>>(
            x, h16, offs, node_offs, bflag, recs, out);
    } else {
        const int total = nd + N_EDGES;
        init_out_kernel<<<(total + 255) / 256, 256, 0, stream>>>(x, out, nd, total);
        long long threads = (long long)N_EDGES * 64;
        edge_scatter_kernel<<<(int)((threads + 255) / 256), 256, 0, stream>>>(
            x, x + nd, src, dst, out);
    }
}

// Round 12
// 174.192 us; speedup vs baseline: 1.0611x; 1.0611x over previous
//
#include <hip/hip_runtime.h>

#define N_NODES 100000
#define D_FEAT  64
#define N_EDGES 3200000
#define GAMMA   0.5f

#define BSH   8                                   // 256 nodes per bucket
#define BN    (1 << BSH)                          // 256
#define NB    ((N_NODES + BN - 1) >> BSH)         // 391 buckets
#define NBP   512                                 // pow2 pad for scans

#define H_BLOCKS 1000
#define H_EPB    3200                             // edges per hist block (800 int4)

#define CVT_V4     (N_NODES * D_FEAT / 4)         // 1,600,000 float4
#define CVT_BLOCKS ((CVT_V4 + 255) / 256)         // 6250

#define K1_CH    4096                             // edges per K1 block
#define K1_BLOCKS ((N_EDGES + K1_CH - 1) / K1_CH) // 782

#define K2_CAP   10240                            // max recs sortable in LDS

#define SRC_MASK 0x1FFFFu                         // 17 bits for src

// ---- P0: fused [dst-bucket histogram (int4) + zero edge-out] | [h f32->bf16] ----
__global__ void pre_kernel(const float* __restrict__ h,
                           const int* __restrict__ dst,
                           unsigned short* __restrict__ h16,
                           int* __restrict__ counts,
                           float* __restrict__ out_edge) {
    __shared__ int lcnt[NB];
    const int bid = blockIdx.x;
    if (bid < H_BLOCKS) {
        for (int i = threadIdx.x; i < NB; i += 256) lcnt[i] = 0;
        __syncthreads();
        const int4*  dst4 = (const int4*)(dst + bid * H_EPB);
        float4*      oe4  = (float4*)(out_edge + bid * H_EPB);
        const float4 z4   = make_float4(0.f, 0.f, 0.f, 0.f);
        for (int i = threadIdx.x; i < H_EPB / 4; i += 256) {
            int4 d = dst4[i];
            __hip_atomic_fetch_add(&lcnt[d.x >> BSH], 1, __ATOMIC_RELAXED, __HIP_MEMORY_SCOPE_WORKGROUP);
            __hip_atomic_fetch_add(&lcnt[d.y >> BSH], 1, __ATOMIC_RELAXED, __HIP_MEMORY_SCOPE_WORKGROUP);
            __hip_atomic_fetch_add(&lcnt[d.z >> BSH], 1, __ATOMIC_RELAXED, __HIP_MEMORY_SCOPE_WORKGROUP);
            __hip_atomic_fetch_add(&lcnt[d.w >> BSH], 1, __ATOMIC_RELAXED, __HIP_MEMORY_SCOPE_WORKGROUP);
            oe4[i] = z4;
        }
        __syncthreads();
        for (int i = threadIdx.x; i < NB; i += 256) {
            int c = lcnt[i];
            if (c) atomicAdd(&counts[i], c);
        }
    } else {
        int i = (bid - H_BLOCKS) * 256 + threadIdx.x;
        if (i < CVT_V4) {
            float4 v = ((const float4*)h)[i];
            ushort4 o;
            unsigned u;
            u = __float_as_uint(v.x); o.x = (unsigned short)((u + 0x7fffu + ((u >> 16) & 1u)) >> 16);
            u = __float_as_uint(v.y); o.y = (unsigned short)((u + 0x7fffu + ((u >> 16) & 1u)) >> 16);
            u = __float_as_uint(v.z); o.z = (unsigned short)((u + 0x7fffu + ((u >> 16) & 1u)) >> 16);
            u = __float_as_uint(v.w); o.w = (unsigned short)((u + 0x7fffu + ((u >> 16) & 1u)) >> 16);
            ((ushort4*)h16)[i] = o;
        }
    }
}

// ---- P1: scan 391 bucket counts -> offs/curs; init bflag, node_offs tail ----
__global__ void scan_kernel(const int* __restrict__ counts,
                            int* __restrict__ offs,
                            int* __restrict__ curs,
                            int* __restrict__ bflag,
                            int* __restrict__ node_offs) {
    __shared__ int sb[NBP];
    int t = threadIdx.x;
    int c = (t < NB) ? counts[t] : 0;
    sb[t] = c;
    __syncthreads();
    for (int off = 1; off < NBP; off <<= 1) {
        int v = 0;
        if (t >= off) v = sb[t - off];
        __syncthreads();
        sb[t] += v;
        __syncthreads();
    }
    if (t < NB) {
        offs[t] = sb[t] - c;
        curs[t] = sb[t] - c;
        bflag[t] = 0;
    }
    if (t == NBP - 1) offs[NB] = sb[t];
    if (t == 0) node_offs[N_NODES] = N_EDGES;
}

// ---- K1: chunk-local LDS sort by bucket + burst copy (proven R6/R10 form),
// scan replaced by wave-shfl two-level (2 barriers vs 18).
__global__ void __launch_bounds__(512)
bucket_scatter_kernel(const int* __restrict__ src,
                      const int* __restrict__ dst,
                      const float* __restrict__ e,
                      int* __restrict__ curs,
                      uint2* __restrict__ recs) {
    __shared__ uint2          stage[K1_CH];       // 32 KB
    __shared__ unsigned short bkt16[K1_CH];       // 8 KB
    __shared__ int hist[NB], ebuf[NB], cur[NB], gbase[NB];  // 6.3 KB
    __shared__ int wsum[8];

    const int t    = threadIdx.x;
    const int lane = t & 63;
    const int wid  = t >> 6;
    const int base = blockIdx.x * K1_CH;
    int chcnt = N_EDGES - base; if (chcnt > K1_CH) chcnt = K1_CH;

    int dv[8];                                    // register-cached dst
    for (int i = t; i < NB; i += 512) hist[i] = 0;
    __syncthreads();
#pragma unroll
    for (int j = 0; j < 8; ++j) {
        int i = j * 512 + t;
        if (i < chcnt) {
            dv[j] = dst[base + i];
            __hip_atomic_fetch_add(&hist[dv[j] >> BSH], 1,
                                   __ATOMIC_RELAXED, __HIP_MEMORY_SCOPE_WORKGROUP);
        } else dv[j] = -1;
    }
    __syncthreads();
    // two-level scan over NB bins: wave shfl inclusive + cross-wave prefix
    int c = 0, incl = 0;
    if (t < NB) { c = hist[t]; incl = c; }
    for (int s = 1; s < 64; s <<= 1) {
        int u = __shfl_up(incl, s, 64);
        if (lane >= s) incl += u;
    }
    if (lane == 63 && wid < 7) wsum[wid] = incl;  // waves 0..5 fully in-range
    __syncthreads();
    if (t < NB) {
        int pre = 0;
        for (int w = 0; w < wid; ++w) pre += wsum[w];
        ebuf[t] = pre + incl - c;
        cur[t]  = 0;
        gbase[t] = c ? atomicAdd(&curs[t], c) : 0;
    }
    __syncthreads();
#pragma unroll
    for (int j = 0; j < 8; ++j) {
        int i = j * 512 + t;
        if (dv[j] >= 0) {
            int gi = base + i;
            int b  = dv[j] >> BSH;
            int p  = ebuf[b] + __hip_atomic_fetch_add(&cur[b], 1,
                            __ATOMIC_RELAXED, __HIP_MEMORY_SCOPE_WORKGROUP);
            unsigned pk = (unsigned)src[gi] | ((unsigned)(dv[j] & (BN - 1)) << 17);
            stage[p] = make_uint2(pk, __float_as_uint(e[gi]));
            bkt16[p] = (unsigned short)b;
        }
    }
    __syncthreads();
    for (int i = t; i < chcnt; i += 512) {
        int b = bkt16[i];
        recs[gbase[b] + (i - ebuf[b])] = stage[i];
    }
}

// ---- K2: per-bucket node-level sort (in LDS, in place) + node_offs ----
// wave-shfl two-level scan (2 barriers)
__global__ void __launch_bounds__(512)
node_sort_kernel(const int* __restrict__ offs,
                 uint2* __restrict__ recs,
                 int* __restrict__ bflag,
                 int* __restrict__ node_offs) {
    __shared__ uint2 buf[K2_CAP];                 // 80 KB
    __shared__ int hist[BN], ebuf[BN], cur[BN];
    __shared__ int wsum[4];

    const int b    = blockIdx.x;
    const int t    = threadIdx.x;
    const int lane = t & 63;
    const int wid  = t >> 6;
    const int lo   = offs[b];
    const int cnt  = offs[b + 1] - lo;

    if (cnt > K2_CAP) {                           // overflow fallback (rare)
        if (t == 0) bflag[b] = 1;
        if (t < BN) {
            int g = (b << BSH) + t;
            if (g < N_NODES) node_offs[g] = lo;
        }
        return;
    }

    if (t < BN) hist[t] = 0;
    __syncthreads();
    for (int i = t; i < cnt; i += 512) {
        uint2 r = recs[lo + i];
        buf[i] = r;
        __hip_atomic_fetch_add(&hist[r.x >> 17], 1,
                               __ATOMIC_RELAXED, __HIP_MEMORY_SCOPE_WORKGROUP);
    }
    __syncthreads();
    int c = 0, incl = 0;
    if (t < BN) { c = hist[t]; incl = c; }
    for (int s = 1; s < 64; s <<= 1) {
        int u = __shfl_up(incl, s, 64);
        if (lane >= s) incl += u;
    }
    if (t < BN && lane == 63) wsum[wid] = incl;
    __syncthreads();
    if (t < BN) {
        int pre = 0;
        for (int w = 0; w < wid; ++w) pre += wsum[w];
        int exc = pre + incl - c;
        ebuf[t] = exc;
        cur[t]  = 0;
        int g = (b << BSH) + t;
        if (g < N_NODES) node_offs[g] = lo + exc;
    }
    __syncthreads();
    for (int i = t; i < cnt; i += 512) {
        uint2 r = buf[i];
        int dl = r.x >> 17;
        int p  = lo + ebuf[dl] + __hip_atomic_fetch_add(&cur[dl], 1,
                        __ATOMIC_RELAXED, __HIP_MEMORY_SCOPE_WORKGROUP);
        recs[p] = r;
    }
}

// ---- K3 (bf16 h): wave = node; 8 groups x 8 lanes; uint4 row loads ----
__global__ void __launch_bounds__(512)
gather_bf16_kernel(const float* __restrict__ h,
                   const unsigned short* __restrict__ h16,
                   const int* __restrict__ offs,
                   const int* __restrict__ node_offs,
                   const int* __restrict__ bflag,
                   const uint2* __restrict__ recs,
                   float* __restrict__ out) {
    const int wid = threadIdx.x >> 6;
    const int n   = blockIdx.x * 8 + wid;
    if (n >= N_NODES) return;
    const int lane = threadIdx.x & 63;
    const int g    = lane >> 3;        // 0..7
    const int sub  = lane & 7;         // 0..7
    const int b    = n >> BSH;

    const uint4* __restrict__ hv = (const uint4*)h16;   // 8 uint4 per row

    float a0=0.f,a1=0.f,a2=0.f,a3=0.f,a4=0.f,a5=0.f,a6=0.f,a7=0.f;

#define ACC_REC(r)                                                          \
    {                                                                       \
        uint4 v = hv[(r.x & SRC_MASK) * 8 + sub];                           \
        float w = __uint_as_float(r.y);                                     \
        a0 += __uint_as_float(v.x << 16) * w;                               \
        a1 += __uint_as_float(v.x & 0xFFFF0000u) * w;                       \
        a2 += __uint_as_float(v.y << 16) * w;                               \
        a3 += __uint_as_float(v.y & 0xFFFF0000u) * w;                       \
        a4 += __uint_as_float(v.z << 16) * w;                               \
        a5 += __uint_as_float(v.z & 0xFFFF0000u) * w;                       \
        a6 += __uint_as_float(v.w << 16) * w;                               \
        a7 += __uint_as_float(v.w & 0xFFFF0000u) * w;                       \
    }

    if (!bflag[b]) {
        const int lo = node_offs[n], hi = node_offs[n + 1];
        int kk = lo + g;
        while (kk < hi) {
            uint2 r0 = recs[kk];
            uint2 r1 = (kk +  8 < hi) ? recs[kk +  8] : make_uint2(0u, 0u);
            uint2 r2 = (kk + 16 < hi) ? recs[kk + 16] : make_uint2(0u, 0u);
            uint2 r3 = (kk + 24 < hi) ? recs[kk + 24] : make_uint2(0u, 0u);
            ACC_REC(r0); ACC_REC(r1); ACC_REC(r2); ACC_REC(r3);
            kk += 32;
        }
    } else {                                      // unsorted bucket: scan-match
        const int lo = offs[b], hi = offs[b + 1];
        const unsigned dl = (unsigned)(n & (BN - 1));
        for (int k = lo + g; k < hi; k += 8) {
            uint2 r = recs[k];
            if ((r.x >> 17) == dl) ACC_REC(r);
        }
    }
#undef ACC_REC

    for (int m = 8; m <= 32; m <<= 1) {
        a0 += __shfl_xor(a0, m); a1 += __shfl_xor(a1, m);
        a2 += __shfl_xor(a2, m); a3 += __shfl_xor(a3, m);
        a4 += __shfl_xor(a4, m); a5 += __shfl_xor(a5, m);
        a6 += __shfl_xor(a6, m); a7 += __shfl_xor(a7, m);
    }

    if (g == 0) {
        const float4* __restrict__ h4 = (const float4*)h;
        const int o = n * 16 + sub * 2;
        float4 p = h4[o], q = h4[o + 1];
        float4 r0, r1;
        r0.x = a0 - GAMMA * p.x; r0.y = a1 - GAMMA * p.y;
        r0.z = a2 - GAMMA * p.z; r0.w = a3 - GAMMA * p.w;
        r1.x = a4 - GAMMA * q.x; r1.y = a5 - GAMMA * q.y;
        r1.z = a6 - GAMMA * q.z; r1.w = a7 - GAMMA * q.w;
        ((float4*)out)[o]     = r0;
        ((float4*)out)[o + 1] = r1;
    }
}

// ---------------- fallback atomic path (if ws too small) ----------------
__global__ void init_out_kernel(const float* __restrict__ x,
                                float* __restrict__ out,
                                int nd, int total) {
    int i = blockIdx.x * blockDim.x + threadIdx.x;
    if (i < nd)         out[i] = -GAMMA * x[i];
    else if (i < total) out[i] = 0.0f;
}

__global__ void edge_scatter_kernel(const float* __restrict__ h,
                                    const float* __restrict__ e,
                                    const int* __restrict__ src,
                                    const int* __restrict__ dst,
                                    float* __restrict__ out) {
    long long idx = (long long)blockIdx.x * blockDim.x + threadIdx.x;
    int edge = (int)(idx >> 6);
    int d    = (int)(idx & 63);
    if (edge >= N_EDGES) return;
    atomicAdd(&out[dst[edge] * D_FEAT + d], h[src[edge] * D_FEAT + d] * e[edge]);
}

// ---------------- launch ----------------
extern "C" void kernel_launch(void* const* d_in, const int* in_sizes, int n_in,
                              void* d_out, int out_size, void* d_ws, size_t ws_size,
                              hipStream_t stream) {
    const float* x   = (const float*)d_in[1];
    const int*   src = (const int*)d_in[2];
    const int*   dst = (const int*)d_in[3];
    float*       out = (float*)d_out;

    const int nd = N_NODES * D_FEAT;

    // ws: counts[NB] | offs[NB+1] | curs[NB] | bflag[NB] | node_offs[N+1] |
    //     pad->256B | recs[E] (uint2) | pad->256B | h16[nd]   (layout frozen from R10)
    size_t ints    = (size_t)NB * 4 + 1 + (size_t)N_NODES + 1;
    size_t rec_off = (ints * 4 + 255) & ~(size_t)255;
    size_t h16_off = (rec_off + (size_t)N_EDGES * 8 + 255) & ~(size_t)255;
    size_t needed  = h16_off + (size_t)nd * 2;

    if (ws_size >= needed) {
        int*   counts    = (int*)d_ws;
        int*   offs      = counts + NB;
        int*   curs      = offs + NB + 1;
        int*   bflag     = curs + NB;
        int*   node_offs = bflag + NB;
        uint2* recs      = (uint2*)((char*)d_ws + rec_off);
        unsigned short* h16 = (unsigned short*)((char*)d_ws + h16_off);

        hipMemsetAsync(counts, 0, NB * sizeof(int), stream);
        pre_kernel<<<H_BLOCKS + CVT_BLOCKS, 256, 0, stream>>>(x, dst, h16, counts, out + nd);
        scan_kernel<<<1, NBP, 0, stream>>>(counts, offs, curs, bflag, node_offs);
        bucket_scatter_kernel<<<K1_BLOCKS, 512, 0, stream>>>(src, dst, x + nd, curs, recs);
        node_sort_kernel<<<NB, 512, 0, stream>>>(offs, recs, bflag, node_offs);
        gather_bf16_kernel<<<(N_NODES + 7) / 8, 512, 0, stream>>>(
            x, h16, offs, node_offs, bflag, recs, out);
    } else {
        const int total = nd + N_EDGES;
        init_out_kernel<<<(total + 255) / 256, 256, 0, stream>>>(x, out, nd, total);
        long long threads = (long long)N_EDGES * 64;
        edge_scatter_kernel<<<(int)((threads + 255) / 256), 256, 0, stream>>>(
            x, x + nd, src, dst, out);
    }
}

// Round 13
// 152.476 us; speedup vs baseline: 1.2123x; 1.1424x over previous
//
#include <hip/hip_runtime.h>

#define N_NODES 100000
#define D_FEAT  64
#define N_EDGES 3200000
#define GAMMA   0.5f

#define BSH   8                                   // 256 nodes per bucket
#define BN    (1 << BSH)                          // 256
#define NB    391                                 // buckets
#define CH    2048                                // edges per chunk
#define NC    ((N_EDGES + CH - 1) / CH)           // 1563 chunks

#define Z_BLOCKS   782                            // edge-zero blocks (4 float4/thr)
#define CVT_V4     (N_NODES * D_FEAT / 4)         // 1,600,000 float4
#define CVT_BLOCKS ((CVT_V4 + 255) / 256)         // 6250

#define K2_CAP   10240
#define SRC_MASK 0x1FFFFu

// ---- P0: [per-chunk bucket hist -> mat16] | [zero edge-out] | [h->bf16] ----
__global__ void __launch_bounds__(256)
p0_kernel(const float* __restrict__ h,
          const int* __restrict__ dst,
          unsigned short* __restrict__ h16,
          unsigned short* __restrict__ mat,
          float* __restrict__ out_edge) {
    __shared__ int hist[NB];
    const int bid = blockIdx.x;
    const int t   = threadIdx.x;
    if (bid < NC) {
        for (int i = t; i < NB; i += 256) hist[i] = 0;
        __syncthreads();
        const int base  = bid * CH;
        const int chcnt = min(N_EDGES - base, CH);
#pragma unroll
        for (int j = 0; j < 8; ++j) {
            int i = j * 256 + t;
            if (i < chcnt)
                __hip_atomic_fetch_add(&hist[dst[base + i] >> BSH], 1,
                                       __ATOMIC_RELAXED, __HIP_MEMORY_SCOPE_WORKGROUP);
        }
        __syncthreads();
        for (int i = t; i < NB; i += 256)
            mat[bid * NB + i] = (unsigned short)hist[i];
    } else if (bid < NC + Z_BLOCKS) {
        float4* oe4 = (float4*)out_edge;
        const int b2 = bid - NC;
        const float4 z = make_float4(0.f, 0.f, 0.f, 0.f);
#pragma unroll
        for (int j = 0; j < 4; ++j) {
            int i = b2 * 1024 + j * 256 + t;
            if (i < N_EDGES / 4) oe4[i] = z;
        }
    } else {
        int i = (bid - NC - Z_BLOCKS) * 256 + t;
        if (i < CVT_V4) {
            float4 v = ((const float4*)h)[i];
            ushort4 o;
            unsigned u;
            u = __float_as_uint(v.x); o.x = (unsigned short)((u + 0x7fffu + ((u >> 16) & 1u)) >> 16);
            u = __float_as_uint(v.y); o.y = (unsigned short)((u + 0x7fffu + ((u >> 16) & 1u)) >> 16);
            u = __float_as_uint(v.z); o.z = (unsigned short)((u + 0x7fffu + ((u >> 16) & 1u)) >> 16);
            u = __float_as_uint(v.w); o.w = (unsigned short)((u + 0x7fffu + ((u >> 16) & 1u)) >> 16);
            ((ushort4*)h16)[i] = o;
        }
    }
}

// ---- M1: in-place exclusive scan of each bucket row across chunks ----
// block b, 64 lanes: mat[c][b] -> prefix rel; rowsum[b] = bucket total.
__global__ void __launch_bounds__(64)
matscan_kernel(unsigned short* __restrict__ mat,
               int* __restrict__ rowsum) {
    const int b = blockIdx.x;
    const int l = threadIdx.x;
    int carry = 0;
    for (int r = 0; r < (NC + 63) / 64; ++r) {
        int c = r * 64 + l;
        int v = (c < NC) ? (int)mat[c * NB + b] : 0;
        int incl = v;
        for (int s = 1; s < 64; s <<= 1) {
            int u = __shfl_up(incl, s, 64);
            if (l >= s) incl += u;
        }
        if (c < NC) mat[c * NB + b] = (unsigned short)(carry + incl - v);
        carry += __shfl(incl, 63, 64);
    }
    if (l == 0) rowsum[b] = carry;
}

// ---- K1c: chunk sort + scatter, zero global atomics (positions from mat) ----
__global__ void __launch_bounds__(256)
bucket_scatter_kernel(const int* __restrict__ src,
                      const int* __restrict__ dst,
                      const float* __restrict__ e,
                      const unsigned short* __restrict__ mat,
                      const int* __restrict__ rowsum,
                      int* __restrict__ offs_g,
                      uint2* __restrict__ recs) {
    __shared__ uint2          stage[CH];          // 16 KB
    __shared__ unsigned short bkt[CH];            // 4 KB
    __shared__ int hist[NB], ebuf[NB], cur[NB], gb[NB];
    __shared__ int offsL[NB + 1];
    __shared__ int wsum[4];

    const int t    = threadIdx.x;
    const int lane = t & 63;
    const int wid  = t >> 6;
    const int c    = blockIdx.x;
    const int base = c * CH;
    const int chcnt = min(N_EDGES - base, CH);
    const int i0 = 2 * t, i1 = 2 * t + 1;

    // zero hist; offs scan phase 1 (rowsum pairs -> wave incl)
    for (int i = t; i < NB; i += 256) hist[i] = 0;
    int a  = (i0 < NB) ? rowsum[i0] : 0;
    int d1 = (i1 < NB) ? rowsum[i1] : 0;
    int pair = a + d1, incl = pair;
    for (int s = 1; s < 64; s <<= 1) {
        int u = __shfl_up(incl, s, 64);
        if (lane >= s) incl += u;
    }
    if (lane == 63) wsum[wid] = incl;
    __syncthreads();
    {
        int pre = 0;
        for (int w = 0; w < wid; ++w) pre += wsum[w];
        int excl = pre + incl - pair;
        if (i0 < NB) offsL[i0] = excl;
        if (i1 < NB) offsL[i1] = excl + a;
        if (t == 255) offsL[NB] = pre + incl;     // == N_EDGES
    }
    // dst register cache + local hist
    int dv[8];
#pragma unroll
    for (int j = 0; j < 8; ++j) {
        int i = j * 256 + t;
        if (i < chcnt) {
            dv[j] = dst[base + i];
            __hip_atomic_fetch_add(&hist[dv[j] >> BSH], 1,
                                   __ATOMIC_RELAXED, __HIP_MEMORY_SCOPE_WORKGROUP);
        } else dv[j] = -1;
    }
    __syncthreads();                              // hist final, wsum reusable
    // local scan of hist (2 bins/thread)
    int c0 = (i0 < NB) ? hist[i0] : 0;
    int c1 = (i1 < NB) ? hist[i1] : 0;
    int p2 = c0 + c1, incl2 = p2;
    for (int s = 1; s < 64; s <<= 1) {
        int u = __shfl_up(incl2, s, 64);
        if (lane >= s) incl2 += u;
    }
    if (lane == 63) wsum[wid] = incl2;
    __syncthreads();
    {
        int pre = 0;
        for (int w = 0; w < wid; ++w) pre += wsum[w];
        int excl2 = pre + incl2 - p2;
        if (i0 < NB) {
            ebuf[i0] = excl2;
            cur[i0]  = 0;
            gb[i0]   = offsL[i0] + (int)mat[c * NB + i0];
        }
        if (i1 < NB) {
            ebuf[i1] = excl2 + c0;
            cur[i1]  = 0;
            gb[i1]   = offsL[i1] + (int)mat[c * NB + i1];
        }
    }
    __syncthreads();
    // pass 2: stage sort into LDS
#pragma unroll
    for (int j = 0; j < 8; ++j) {
        if (dv[j] >= 0) {
            int gi = base + j * 256 + t;
            int b  = dv[j] >> BSH;
            int p  = ebuf[b] + __hip_atomic_fetch_add(&cur[b], 1,
                            __ATOMIC_RELAXED, __HIP_MEMORY_SCOPE_WORKGROUP);
            unsigned pk = (unsigned)src[gi] | ((unsigned)(dv[j] & (BN - 1)) << 17);
            stage[p] = make_uint2(pk, __float_as_uint(e[gi]));
            bkt[p]   = (unsigned short)b;
        }
    }
    __syncthreads();
    // burst copy to global (bucket-contiguous)
    for (int i = t; i < chcnt; i += 256) {
        int b = bkt[i];
        recs[gb[b] + (i - ebuf[b])] = stage[i];
    }
    // block 0 materializes offs for K2/gather
    if (c == 0) {
        for (int i = t; i <= NB; i += 256) offs_g[i] = offsL[i];
    }
}

// ---- K2: per-bucket node-level sort (in LDS, in place) + node_offs/bflag ----
__global__ void __launch_bounds__(512)
node_sort_kernel(const int* __restrict__ offs,
                 uint2* __restrict__ recs,
                 int* __restrict__ bflag,
                 int* __restrict__ node_offs) {
    __shared__ uint2 buf[K2_CAP];                 // 80 KB
    __shared__ int hist[BN], ebuf[BN], cur[BN];
    __shared__ int wsum[4];

    const int b    = blockIdx.x;
    const int t    = threadIdx.x;
    const int lane = t & 63;
    const int wid  = t >> 6;
    const int lo   = offs[b];
    const int cnt  = offs[b + 1] - lo;

    if (b == NB - 1 && t == 0) node_offs[N_NODES] = N_EDGES;

    if (cnt > K2_CAP) {                           // overflow fallback (never expected)
        if (t == 0) bflag[b] = 1;
        if (t < BN) {
            int g = (b << BSH) + t;
            if (g < N_NODES) node_offs[g] = lo;
        }
        return;
    }
    if (t == 0) bflag[b] = 0;

    if (t < BN) hist[t] = 0;
    __syncthreads();
    for (int i = t; i < cnt; i += 512) {
        uint2 r = recs[lo + i];
        buf[i] = r;
        __hip_atomic_fetch_add(&hist[r.x >> 17], 1,
                               __ATOMIC_RELAXED, __HIP_MEMORY_SCOPE_WORKGROUP);
    }
    __syncthreads();
    int c = 0, incl = 0;
    if (t < BN) { c = hist[t]; incl = c; }
    for (int s = 1; s < 64; s <<= 1) {
        int u = __shfl_up(incl, s, 64);
        if (lane >= s) incl += u;
    }
    if (t < BN && lane == 63) wsum[wid] = incl;
    __syncthreads();
    if (t < BN) {
        int pre = 0;
        for (int w = 0; w < wid; ++w) pre += wsum[w];
        int exc = pre + incl - c;
        ebuf[t] = exc;
        cur[t]  = 0;
        int g = (b << BSH) + t;
        if (g < N_NODES) node_offs[g] = lo + exc;
    }
    __syncthreads();
    for (int i = t; i < cnt; i += 512) {
        uint2 r = buf[i];
        int dl = r.x >> 17;
        int p  = lo + ebuf[dl] + __hip_atomic_fetch_add(&cur[dl], 1,
                        __ATOMIC_RELAXED, __HIP_MEMORY_SCOPE_WORKGROUP);
        recs[p] = r;
    }
}

// ---- K3 (bf16 h): wave = node; 8 groups x 8 lanes; uint4 row loads ----
__global__ void __launch_bounds__(512)
gather_bf16_kernel(const float* __restrict__ h,
                   const unsigned short* __restrict__ h16,
                   const int* __restrict__ offs,
                   const int* __restrict__ node_offs,
                   const int* __restrict__ bflag,
                   const uint2* __restrict__ recs,
                   float* __restrict__ out) {
    const int wid = threadIdx.x >> 6;
    const int n   = blockIdx.x * 8 + wid;
    if (n >= N_NODES) return;
    const int lane = threadIdx.x & 63;
    const int g    = lane >> 3;        // 0..7
    const int sub  = lane & 7;         // 0..7
    const int b    = n >> BSH;

    const uint4* __restrict__ hv = (const uint4*)h16;   // 8 uint4 per row

    float a0=0.f,a1=0.f,a2=0.f,a3=0.f,a4=0.f,a5=0.f,a6=0.f,a7=0.f;

#define ACC_REC(r)                                                          \
    {                                                                       \
        uint4 v = hv[(r.x & SRC_MASK) * 8 + sub];                           \
        float w = __uint_as_float(r.y);                                     \
        a0 += __uint_as_float(v.x << 16) * w;                               \
        a1 += __uint_as_float(v.x & 0xFFFF0000u) * w;                       \
        a2 += __uint_as_float(v.y << 16) * w;                               \
        a3 += __uint_as_float(v.y & 0xFFFF0000u) * w;                       \
        a4 += __uint_as_float(v.z << 16) * w;                               \
        a5 += __uint_as_float(v.z & 0xFFFF0000u) * w;                       \
        a6 += __uint_as_float(v.w << 16) * w;                               \
        a7 += __uint_as_float(v.w & 0xFFFF0000u) * w;                       \
    }

    if (!bflag[b]) {
        const int lo = node_offs[n], hi = node_offs[n + 1];
        int kk = lo + g;
        while (kk < hi) {
            uint2 r0 = recs[kk];
            uint2 r1 = (kk +  8 < hi) ? recs[kk +  8] : make_uint2(0u, 0u);
            uint2 r2 = (kk + 16 < hi) ? recs[kk + 16] : make_uint2(0u, 0u);
            uint2 r3 = (kk + 24 < hi) ? recs[kk + 24] : make_uint2(0u, 0u);
            ACC_REC(r0); ACC_REC(r1); ACC_REC(r2); ACC_REC(r3);
            kk += 32;
        }
    } else {                                      // unsorted bucket: scan-match
        const int lo = offs[b], hi = offs[b + 1];
        const unsigned dl = (unsigned)(n & (BN - 1));
        for (int k = lo + g; k < hi; k += 8) {
            uint2 r = recs[k];
            if ((r.x >> 17) == dl) ACC_REC(r);
        }
    }
#undef ACC_REC

    for (int m = 8; m <= 32; m <<= 1) {
        a0 += __shfl_xor(a0, m); a1 += __shfl_xor(a1, m);
        a2 += __shfl_xor(a2, m); a3 += __shfl_xor(a3, m);
        a4 += __shfl_xor(a4, m); a5 += __shfl_xor(a5, m);
        a6 += __shfl_xor(a6, m); a7 += __shfl_xor(a7, m);
    }

    if (g == 0) {
        const float4* __restrict__ h4 = (const float4*)h;
        const int o = n * 16 + sub * 2;
        float4 p = h4[o], q = h4[o + 1];
        float4 r0, r1;
        r0.x = a0 - GAMMA * p.x; r0.y = a1 - GAMMA * p.y;
        r0.z = a2 - GAMMA * p.z; r0.w = a3 - GAMMA * p.w;
        r1.x = a4 - GAMMA * q.x; r1.y = a5 - GAMMA * q.y;
        r1.z = a6 - GAMMA * q.z; r1.w = a7 - GAMMA * q.w;
        ((float4*)out)[o]     = r0;
        ((float4*)out)[o + 1] = r1;
    }
}

// ---------------- fallback atomic path (if ws too small) ----------------
__global__ void init_out_kernel(const float* __restrict__ x,
                                float* __restrict__ out,
                                int nd, int total) {
    int i = blockIdx.x * blockDim.x + threadIdx.x;
    if (i < nd)         out[i] = -GAMMA * x[i];
    else if (i < total) out[i] = 0.0f;
}

__global__ void edge_scatter_kernel(const float* __restrict__ h,
                                    const float* __restrict__ e,
                                    const int* __restrict__ src,
                                    const int* __restrict__ dst,
                                    float* __restrict__ out) {
    long long idx = (long long)blockIdx.x * blockDim.x + threadIdx.x;
    int edge = (int)(idx >> 6);
    int d    = (int)(idx & 63);
    if (edge >= N_EDGES) return;
    atomicAdd(&out[dst[edge] * D_FEAT + d], h[src[edge] * D_FEAT + d] * e[edge]);
}

// ---------------- launch ----------------
extern "C" void kernel_launch(void* const* d_in, const int* in_sizes, int n_in,
                              void* d_out, int out_size, void* d_ws, size_t ws_size,
                              hipStream_t stream) {
    const float* x   = (const float*)d_in[1];
    const int*   src = (const int*)d_in[2];
    const int*   dst = (const int*)d_in[3];
    float*       out = (float*)d_out;

    const int nd = N_NODES * D_FEAT;

    // ws: offs[NB+1] | bflag[NB] | node_offs[N+1] | rowsum[NB] | mat16[NC*NB]
    //     | pad->256 | recs[E] | pad->256 | h16[nd]
    size_t ints    = (size_t)(NB + 1) + NB + (size_t)N_NODES + 1 + NB;
    size_t mat_off = ints * 4;
    size_t rec_off = (mat_off + (size_t)NC * NB * 2 + 255) & ~(size_t)255;
    size_t h16_off = (rec_off + (size_t)N_EDGES * 8 + 255) & ~(size_t)255;
    size_t needed  = h16_off + (size_t)nd * 2;

    if (ws_size >= needed) {
        int* offs      = (int*)d_ws;
        int* bflag     = offs + NB + 1;
        int* node_offs = bflag + NB;
        int* rowsum    = node_offs + N_NODES + 1;
        unsigned short* mat = (unsigned short*)((char*)d_ws + mat_off);
        uint2*          recs = (uint2*)((char*)d_ws + rec_off);
        unsigned short* h16  = (unsigned short*)((char*)d_ws + h16_off);

        p0_kernel<<<NC + Z_BLOCKS + CVT_BLOCKS, 256, 0, stream>>>(
            x, dst, h16, mat, out + nd);
        matscan_kernel<<<NB, 64, 0, stream>>>(mat, rowsum);
        bucket_scatter_kernel<<<NC, 256, 0, stream>>>(
            src, dst, x + nd, mat, rowsum, offs, recs);
        node_sort_kernel<<<NB, 512, 0, stream>>>(offs, recs, bflag, node_offs);
        gather_bf16_kernel<<<(N_NODES + 7) / 8, 512, 0, stream>>>(
            x, h16, offs, node_offs, bflag, recs, out);
    } else {
        const int total = nd + N_EDGES;
        init_out_kernel<<<(total + 255) / 256, 256, 0, stream>>>(x, out, nd, total);
        long long threads = (long long)N_EDGES * 64;
        edge_scatter_kernel<<<(int)((threads + 255) / 256), 256, 0, stream>>>(
            x, x + nd, src, dst, out);
    }
}

// Round 14
// 152.390 us; speedup vs baseline: 1.2130x; 1.0006x over previous
//
#include <hip/hip_runtime.h>

#define N_NODES 100000
#define D_FEAT  64
#define N_EDGES 3200000
#define GAMMA   0.5f

#define BSH   8                                   // 256 nodes per bucket
#define BN    (1 << BSH)                          // 256
#define NB    391                                 // buckets
#define CH    2048                                // edges per chunk
#define NC    ((N_EDGES + CH - 1) / CH)           // 1563 chunks

#define Z_BLOCKS   782                            // edge-zero blocks (4 float4/thr)
#define CVT_V4     (N_NODES * D_FEAT / 4)         // 1,600,000 float4
#define CVT_BLOCKS ((CVT_V4 + 255) / 256)         // 6250

#define K2_REG   20                               // recs cached per thread
#define K2_CAP   (512 * K2_REG)                   // 10240
#define SRC_MASK 0x1FFFFu

// ---- P0: [per-chunk bucket hist -> mat16] | [zero edge-out] | [h->bf16] ----
__global__ void __launch_bounds__(256)
p0_kernel(const float* __restrict__ h,
          const int* __restrict__ dst,
          unsigned short* __restrict__ h16,
          unsigned short* __restrict__ mat,
          float* __restrict__ out_edge) {
    __shared__ int hist[NB];
    const int bid = blockIdx.x;
    const int t   = threadIdx.x;
    if (bid < NC) {
        for (int i = t; i < NB; i += 256) hist[i] = 0;
        __syncthreads();
        const int base  = bid * CH;
        const int chcnt = min(N_EDGES - base, CH);
#pragma unroll
        for (int j = 0; j < 8; ++j) {
            int i = j * 256 + t;
            if (i < chcnt)
                __hip_atomic_fetch_add(&hist[dst[base + i] >> BSH], 1,
                                       __ATOMIC_RELAXED, __HIP_MEMORY_SCOPE_WORKGROUP);
        }
        __syncthreads();
        for (int i = t; i < NB; i += 256)
            mat[bid * NB + i] = (unsigned short)hist[i];
    } else if (bid < NC + Z_BLOCKS) {
        float4* oe4 = (float4*)out_edge;
        const int b2 = bid - NC;
        const float4 z = make_float4(0.f, 0.f, 0.f, 0.f);
#pragma unroll
        for (int j = 0; j < 4; ++j) {
            int i = b2 * 1024 + j * 256 + t;
            if (i < N_EDGES / 4) oe4[i] = z;
        }
    } else {
        int i = (bid - NC - Z_BLOCKS) * 256 + t;
        if (i < CVT_V4) {
            float4 v = ((const float4*)h)[i];
            ushort4 o;
            unsigned u;
            u = __float_as_uint(v.x); o.x = (unsigned short)((u + 0x7fffu + ((u >> 16) & 1u)) >> 16);
            u = __float_as_uint(v.y); o.y = (unsigned short)((u + 0x7fffu + ((u >> 16) & 1u)) >> 16);
            u = __float_as_uint(v.z); o.z = (unsigned short)((u + 0x7fffu + ((u >> 16) & 1u)) >> 16);
            u = __float_as_uint(v.w); o.w = (unsigned short)((u + 0x7fffu + ((u >> 16) & 1u)) >> 16);
            ((ushort4*)h16)[i] = o;
        }
    }
}

// ---- M1: in-place exclusive scan of each bucket row across chunks ----
__global__ void __launch_bounds__(64)
matscan_kernel(unsigned short* __restrict__ mat,
               int* __restrict__ rowsum) {
    const int b = blockIdx.x;
    const int l = threadIdx.x;
    int carry = 0;
    for (int r = 0; r < (NC + 63) / 64; ++r) {
        int c = r * 64 + l;
        int v = (c < NC) ? (int)mat[c * NB + b] : 0;
        int incl = v;
        for (int s = 1; s < 64; s <<= 1) {
            int u = __shfl_up(incl, s, 64);
            if (l >= s) incl += u;
        }
        if (c < NC) mat[c * NB + b] = (unsigned short)(carry + incl - v);
        carry += __shfl(incl, 63, 64);
    }
    if (l == 0) rowsum[b] = carry;
}

// ---- K1c: chunk sort + scatter, zero global atomics (positions from mat) ----
__global__ void __launch_bounds__(256)
bucket_scatter_kernel(const int* __restrict__ src,
                      const int* __restrict__ dst,
                      const float* __restrict__ e,
                      const unsigned short* __restrict__ mat,
                      const int* __restrict__ rowsum,
                      int* __restrict__ offs_g,
                      uint2* __restrict__ recs) {
    __shared__ uint2          stage[CH];          // 16 KB
    __shared__ unsigned short bkt[CH];            // 4 KB
    __shared__ int hist[NB], ebuf[NB], cur[NB], gb[NB];
    __shared__ int offsL[NB + 1];
    __shared__ int wsum[4];

    const int t    = threadIdx.x;
    const int lane = t & 63;
    const int wid  = t >> 6;
    const int c    = blockIdx.x;
    const int base = c * CH;
    const int chcnt = min(N_EDGES - base, CH);
    const int i0 = 2 * t, i1 = 2 * t + 1;

    for (int i = t; i < NB; i += 256) hist[i] = 0;
    int a  = (i0 < NB) ? rowsum[i0] : 0;
    int d1 = (i1 < NB) ? rowsum[i1] : 0;
    int pair = a + d1, incl = pair;
    for (int s = 1; s < 64; s <<= 1) {
        int u = __shfl_up(incl, s, 64);
        if (lane >= s) incl += u;
    }
    if (lane == 63) wsum[wid] = incl;
    __syncthreads();
    {
        int pre = 0;
        for (int w = 0; w < wid; ++w) pre += wsum[w];
        int excl = pre + incl - pair;
        if (i0 < NB) offsL[i0] = excl;
        if (i1 < NB) offsL[i1] = excl + a;
        if (t == 255) offsL[NB] = pre + incl;     // == N_EDGES
    }
    int dv[8];
#pragma unroll
    for (int j = 0; j < 8; ++j) {
        int i = j * 256 + t;
        if (i < chcnt) {
            dv[j] = dst[base + i];
            __hip_atomic_fetch_add(&hist[dv[j] >> BSH], 1,
                                   __ATOMIC_RELAXED, __HIP_MEMORY_SCOPE_WORKGROUP);
        } else dv[j] = -1;
    }
    __syncthreads();
    int c0 = (i0 < NB) ? hist[i0] : 0;
    int c1 = (i1 < NB) ? hist[i1] : 0;
    int p2 = c0 + c1, incl2 = p2;
    for (int s = 1; s < 64; s <<= 1) {
        int u = __shfl_up(incl2, s, 64);
        if (lane >= s) incl2 += u;
    }
    if (lane == 63) wsum[wid] = incl2;
    __syncthreads();
    {
        int pre = 0;
        for (int w = 0; w < wid; ++w) pre += wsum[w];
        int excl2 = pre + incl2 - p2;
        if (i0 < NB) {
            ebuf[i0] = excl2;
            cur[i0]  = 0;
            gb[i0]   = offsL[i0] + (int)mat[c * NB + i0];
        }
        if (i1 < NB) {
            ebuf[i1] = excl2 + c0;
            cur[i1]  = 0;
            gb[i1]   = offsL[i1] + (int)mat[c * NB + i1];
        }
    }
    __syncthreads();
#pragma unroll
    for (int j = 0; j < 8; ++j) {
        if (dv[j] >= 0) {
            int gi = base + j * 256 + t;
            int b  = dv[j] >> BSH;
            int p  = ebuf[b] + __hip_atomic_fetch_add(&cur[b], 1,
                            __ATOMIC_RELAXED, __HIP_MEMORY_SCOPE_WORKGROUP);
            unsigned pk = (unsigned)src[gi] | ((unsigned)(dv[j] & (BN - 1)) << 17);
            stage[p] = make_uint2(pk, __float_as_uint(e[gi]));
            bkt[p]   = (unsigned short)b;
        }
    }
    __syncthreads();
    for (int i = t; i < chcnt; i += 256) {
        int b = bkt[i];
        recs[gb[b] + (i - ebuf[b])] = stage[i];
    }
    if (c == 0) {
        for (int i = t; i <= NB; i += 256) offs_g[i] = offsL[i];
    }
}

// ---- K2v2: per-bucket node sort, reg-cached, in-place, LDS 3KB ----
__global__ void __launch_bounds__(512)
node_sort_kernel(const int* __restrict__ offs,
                 uint2* __restrict__ recs,
                 int* __restrict__ bflag,
                 int* __restrict__ node_offs) {
    __shared__ int hist[BN], ebuf[BN], cur[BN];
    __shared__ int wsum[4];

    const int b    = blockIdx.x;
    const int t    = threadIdx.x;
    const int lane = t & 63;
    const int wid  = t >> 6;
    const int lo   = offs[b];
    const int cnt  = offs[b + 1] - lo;

    if (b == NB - 1 && t == 0) node_offs[N_NODES] = N_EDGES;

    if (cnt > K2_CAP) {                           // overflow fallback (never expected)
        if (t == 0) bflag[b] = 1;
        if (t < BN) {
            int g = (b << BSH) + t;
            if (g < N_NODES) node_offs[g] = lo;
        }
        return;
    }
    if (t == 0) bflag[b] = 0;
    if (t < BN) hist[t] = 0;
    __syncthreads();

    // read recs into registers + histogram
    uint2 r[K2_REG];
#pragma unroll
    for (int j = 0; j < K2_REG; ++j) {
        int i = j * 512 + t;
        if (i < cnt) {
            r[j] = recs[lo + i];
            __hip_atomic_fetch_add(&hist[r[j].x >> 17], 1,
                                   __ATOMIC_RELAXED, __HIP_MEMORY_SCOPE_WORKGROUP);
        } else r[j].x = 0xFFFFFFFFu;
    }
    __syncthreads();
    // shfl two-level exclusive scan of 256 bins
    int c = 0, incl = 0;
    if (t < BN) { c = hist[t]; incl = c; }
    for (int s = 1; s < 64; s <<= 1) {
        int u = __shfl_up(incl, s, 64);
        if (lane >= s) incl += u;
    }
    if (t < BN && lane == 63) wsum[wid] = incl;
    __syncthreads();
    if (t < BN) {
        int pre = 0;
        for (int w = 0; w < wid; ++w) pre += wsum[w];
        int exc = pre + incl - c;
        ebuf[t] = exc;
        cur[t]  = 0;
        int g = (b << BSH) + t;
        if (g < N_NODES) node_offs[g] = lo + exc;
    }
    __syncthreads();
    // all reads done -> in-place sorted write-back
#pragma unroll
    for (int j = 0; j < K2_REG; ++j) {
        if (r[j].x != 0xFFFFFFFFu) {
            int dl = r[j].x >> 17;
            int p  = lo + ebuf[dl] + __hip_atomic_fetch_add(&cur[dl], 1,
                            __ATOMIC_RELAXED, __HIP_MEMORY_SCOPE_WORKGROUP);
            recs[p] = r[j];
        }
    }
}

// ---- K3 (bf16 h): wave = node; 8 groups x 8 lanes; uint4 row loads;
// recs loaded nontemporally (streamed once - keep L2 for h16).
__global__ void __launch_bounds__(512)
gather_bf16_kernel(const float* __restrict__ h,
                   const unsigned short* __restrict__ h16,
                   const int* __restrict__ offs,
                   const int* __restrict__ node_offs,
                   const int* __restrict__ bflag,
                   const uint2* __restrict__ recs,
                   float* __restrict__ out) {
    const int wid = threadIdx.x >> 6;
    const int n   = blockIdx.x * 8 + wid;
    if (n >= N_NODES) return;
    const int lane = threadIdx.x & 63;
    const int g    = lane >> 3;        // 0..7
    const int sub  = lane & 7;         // 0..7
    const int b    = n >> BSH;

    const uint4* __restrict__ hv = (const uint4*)h16;   // 8 uint4 per row
    const unsigned long long* __restrict__ rq = (const unsigned long long*)recs;

    float a0=0.f,a1=0.f,a2=0.f,a3=0.f,a4=0.f,a5=0.f,a6=0.f,a7=0.f;

#define ACC_Q(q)                                                            \
    {                                                                       \
        unsigned kx = (unsigned)(q);                                        \
        uint4 v = hv[(kx & SRC_MASK) * 8 + sub];                            \
        float w = __uint_as_float((unsigned)((q) >> 32));                   \
        a0 += __uint_as_float(v.x << 16) * w;                               \
        a1 += __uint_as_float(v.x & 0xFFFF0000u) * w;                       \
        a2 += __uint_as_float(v.y << 16) * w;                               \
        a3 += __uint_as_float(v.y & 0xFFFF0000u) * w;                       \
        a4 += __uint_as_float(v.z << 16) * w;                               \
        a5 += __uint_as_float(v.z & 0xFFFF0000u) * w;                       \
        a6 += __uint_as_float(v.w << 16) * w;                               \
        a7 += __uint_as_float(v.w & 0xFFFF0000u) * w;                       \
    }

    if (!bflag[b]) {
        const int lo = node_offs[n], hi = node_offs[n + 1];
        int kk = lo + g;
        while (kk < hi) {
            unsigned long long q0 = __builtin_nontemporal_load(&rq[kk]);
            unsigned long long q1 = (kk +  8 < hi) ? __builtin_nontemporal_load(&rq[kk +  8]) : 0ull;
            unsigned long long q2 = (kk + 16 < hi) ? __builtin_nontemporal_load(&rq[kk + 16]) : 0ull;
            unsigned long long q3 = (kk + 24 < hi) ? __builtin_nontemporal_load(&rq[kk + 24]) : 0ull;
            ACC_Q(q0); ACC_Q(q1); ACC_Q(q2); ACC_Q(q3);
            kk += 32;
        }
    } else {                                      // unsorted bucket: scan-match
        const int lo = offs[b], hi = offs[b + 1];
        const unsigned dl = (unsigned)(n & (BN - 1));
        for (int k = lo + g; k < hi; k += 8) {
            unsigned long long q = rq[k];
            if (((unsigned)q >> 17) == dl) ACC_Q(q);
        }
    }
#undef ACC_Q

    for (int m = 8; m <= 32; m <<= 1) {
        a0 += __shfl_xor(a0, m); a1 += __shfl_xor(a1, m);
        a2 += __shfl_xor(a2, m); a3 += __shfl_xor(a3, m);
        a4 += __shfl_xor(a4, m); a5 += __shfl_xor(a5, m);
        a6 += __shfl_xor(a6, m); a7 += __shfl_xor(a7, m);
    }

    if (g == 0) {
        const float4* __restrict__ h4 = (const float4*)h;
        const int o = n * 16 + sub * 2;
        float4 p = h4[o], q = h4[o + 1];
        float4 r0, r1;
        r0.x = a0 - GAMMA * p.x; r0.y = a1 - GAMMA * p.y;
        r0.z = a2 - GAMMA * p.z; r0.w = a3 - GAMMA * p.w;
        r1.x = a4 - GAMMA * q.x; r1.y = a5 - GAMMA * q.y;
        r1.z = a6 - GAMMA * q.z; r1.w = a7 - GAMMA * q.w;
        ((float4*)out)[o]     = r0;
        ((float4*)out)[o + 1] = r1;
    }
}

// ---------------- fallback atomic path (if ws too small) ----------------
__global__ void init_out_kernel(const float* __restrict__ x,
                                float* __restrict__ out,
                                int nd, int total) {
    int i = blockIdx.x * blockDim.x + threadIdx.x;
    if (i < nd)         out[i] = -GAMMA * x[i];
    else if (i < total) out[i] = 0.0f;
}

__global__ void edge_scatter_kernel(const float* __restrict__ h,
                                    const float* __restrict__ e,
                                    const int* __restrict__ src,
                                    const int* __restrict__ dst,
                                    float* __restrict__ out) {
    long long idx = (long long)blockIdx.x * blockDim.x + threadIdx.x;
    int edge = (int)(idx >> 6);
    int d    = (int)(idx & 63);
    if (edge >= N_EDGES) return;
    atomicAdd(&out[dst[edge] * D_FEAT + d], h[src[edge] * D_FEAT + d] * e[edge]);
}

// ---------------- launch ----------------
extern "C" void kernel_launch(void* const* d_in, const int* in_sizes, int n_in,
                              void* d_out, int out_size, void* d_ws, size_t ws_size,
                              hipStream_t stream) {
    const float* x   = (const float*)d_in[1];
    const int*   src = (const int*)d_in[2];
    const int*   dst = (const int*)d_in[3];
    float*       out = (float*)d_out;

    const int nd = N_NODES * D_FEAT;

    // ws: offs[NB+1] | bflag[NB] | node_offs[N+1] | rowsum[NB] | mat16[NC*NB]
    //     | pad->256 | recs[E] | pad->256 | h16[nd]
    size_t ints    = (size_t)(NB + 1) + NB + (size_t)N_NODES + 1 + NB;
    size_t mat_off = ints * 4;
    size_t rec_off = (mat_off + (size_t)NC * NB * 2 + 255) & ~(size_t)255;
    size_t h16_off = (rec_off + (size_t)N_EDGES * 8 + 255) & ~(size_t)255;
    size_t needed  = h16_off + (size_t)nd * 2;

    if (ws_size >= needed) {
        int* offs      = (int*)d_ws;
        int* bflag     = offs + NB + 1;
        int* node_offs = bflag + NB;
        int* rowsum    = node_offs + N_NODES + 1;
        unsigned short* mat = (unsigned short*)((char*)d_ws + mat_off);
        uint2*          recs = (uint2*)((char*)d_ws + rec_off);
        unsigned short* h16  = (unsigned short*)((char*)d_ws + h16_off);

        p0_kernel<<<NC + Z_BLOCKS + CVT_BLOCKS, 256, 0, stream>>>(
            x, dst, h16, mat, out + nd);
        matscan_kernel<<<NB, 64, 0, stream>>>(mat, rowsum);
        bucket_scatter_kernel<<<NC, 256, 0, stream>>>(
            src, dst, x + nd, mat, rowsum, offs, recs);
        node_sort_kernel<<<NB, 512, 0, stream>>>(offs, recs, bflag, node_offs);
        gather_bf16_kernel<<<(N_NODES + 7) / 8, 512, 0, stream>>>(
            x, h16, offs, node_offs, bflag, recs, out);
    } else {
        const int total = nd + N_EDGES;
        init_out_kernel<<<(total + 255) / 256, 256, 0, stream>>>(x, out, nd, total);
        long long threads = (long long)N_EDGES * 64;
        edge_scatter_kernel<<<(int)((threads + 255) / 256), 256, 0, stream>>>(
            x, x + nd, src, dst, out);
    }
}

// Round 15
// 130.147 us; speedup vs baseline: 1.4203x; 1.1709x over previous
//
#include <hip/hip_runtime.h>

#define N_NODES 100000
#define D_FEAT  64
#define N_EDGES 3200000
#define GAMMA   0.5f

#define BSH   7                                   // 128 nodes per bucket
#define BN    (1 << BSH)                          // 128
#define NB    ((N_NODES + BN - 1) >> BSH)         // 782 buckets
#define CH    2048                                // edges per chunk
#define NC    ((N_EDGES + CH - 1) / CH)           // 1563 chunks

#define Z_BLOCKS   782                            // edge-zero blocks (4 float4/thr)
#define CVT_V4     (N_NODES * D_FEAT / 4)         // 1,600,000 float4
#define CVT_BLOCKS ((CVT_V4 + 255) / 256)         // 6250

#define KG_REG   10                               // recs cached per thread (fused)
#define KG_CAP   4736                             // bucket cap (avg 4092, +10 sigma)
#define SRC_MASK 0x1FFFFu                         // 17 bits for src

// ---- P0: [per-chunk bucket hist -> mat16] | [zero edge-out] | [h->bf16] ----
__global__ void __launch_bounds__(256)
p0_kernel(const float* __restrict__ h,
          const int* __restrict__ dst,
          unsigned short* __restrict__ h16,
          unsigned short* __restrict__ mat,
          float* __restrict__ out_edge) {
    __shared__ int hist[NB];
    const int bid = blockIdx.x;
    const int t   = threadIdx.x;
    if (bid < NC) {
        for (int i = t; i < NB; i += 256) hist[i] = 0;
        __syncthreads();
        const int base  = bid * CH;
        const int chcnt = min(N_EDGES - base, CH);
#pragma unroll
        for (int j = 0; j < 8; ++j) {
            int i = j * 256 + t;
            if (i < chcnt)
                __hip_atomic_fetch_add(&hist[dst[base + i] >> BSH], 1,
                                       __ATOMIC_RELAXED, __HIP_MEMORY_SCOPE_WORKGROUP);
        }
        __syncthreads();
        for (int i = t; i < NB; i += 256)
            mat[bid * NB + i] = (unsigned short)hist[i];
    } else if (bid < NC + Z_BLOCKS) {
        float4* oe4 = (float4*)out_edge;
        const int b2 = bid - NC;
        const float4 z = make_float4(0.f, 0.f, 0.f, 0.f);
#pragma unroll
        for (int j = 0; j < 4; ++j) {
            int i = b2 * 1024 + j * 256 + t;
            if (i < N_EDGES / 4) oe4[i] = z;
        }
    } else {
        int i = (bid - NC - Z_BLOCKS) * 256 + t;
        if (i < CVT_V4) {
            float4 v = ((const float4*)h)[i];
            ushort4 o;
            unsigned u;
            u = __float_as_uint(v.x); o.x = (unsigned short)((u + 0x7fffu + ((u >> 16) & 1u)) >> 16);
            u = __float_as_uint(v.y); o.y = (unsigned short)((u + 0x7fffu + ((u >> 16) & 1u)) >> 16);
            u = __float_as_uint(v.z); o.z = (unsigned short)((u + 0x7fffu + ((u >> 16) & 1u)) >> 16);
            u = __float_as_uint(v.w); o.w = (unsigned short)((u + 0x7fffu + ((u >> 16) & 1u)) >> 16);
            ((ushort4*)h16)[i] = o;
        }
    }
}

// ---- M1: in-place exclusive scan of each bucket row across chunks ----
__global__ void __launch_bounds__(64)
matscan_kernel(unsigned short* __restrict__ mat,
               int* __restrict__ rowsum) {
    const int b = blockIdx.x;
    const int l = threadIdx.x;
    int carry = 0;
    for (int r = 0; r < (NC + 63) / 64; ++r) {
        int c = r * 64 + l;
        int v = (c < NC) ? (int)mat[c * NB + b] : 0;
        int incl = v;
        for (int s = 1; s < 64; s <<= 1) {
            int u = __shfl_up(incl, s, 64);
            if (l >= s) incl += u;
        }
        if (c < NC) mat[c * NB + b] = (unsigned short)(carry + incl - v);
        carry += __shfl(incl, 63, 64);
    }
    if (l == 0) rowsum[b] = carry;
}

// ---- K1: chunk sort + scatter, zero global atomics (positions from mat) ----
__global__ void __launch_bounds__(512)
bucket_scatter_kernel(const int* __restrict__ src,
                      const int* __restrict__ dst,
                      const float* __restrict__ e,
                      const unsigned short* __restrict__ mat,
                      const int* __restrict__ rowsum,
                      int* __restrict__ offs_g,
                      uint2* __restrict__ recs) {
    __shared__ uint2          stage[CH];          // 16 KB
    __shared__ unsigned short bkt[CH];            // 4 KB
    __shared__ int hist[NB], ebuf[NB], cur[NB], gb[NB];  // 12.5 KB
    __shared__ int offsL[NB + 1];                 // 3.1 KB
    __shared__ int wsum[8];

    const int t    = threadIdx.x;
    const int lane = t & 63;
    const int wid  = t >> 6;
    const int c    = blockIdx.x;
    const int base = c * CH;
    const int chcnt = min(N_EDGES - base, CH);
    const int i0 = 2 * t, i1 = 2 * t + 1;

    for (int i = t; i < NB; i += 512) hist[i] = 0;
    // global offs scan from rowsum (2 bins/thread, shfl two-level)
    int a  = (i0 < NB) ? rowsum[i0] : 0;
    int d1 = (i1 < NB) ? rowsum[i1] : 0;
    int pair = a + d1, incl = pair;
    for (int s = 1; s < 64; s <<= 1) {
        int u = __shfl_up(incl, s, 64);
        if (lane >= s) incl += u;
    }
    if (lane == 63) wsum[wid] = incl;
    __syncthreads();
    {
        int pre = 0;
        for (int w = 0; w < wid; ++w) pre += wsum[w];
        int excl = pre + incl - pair;
        if (i0 < NB) offsL[i0] = excl;
        if (i1 < NB) offsL[i1] = excl + a;
        if (t == 511) offsL[NB] = pre + incl;     // == N_EDGES
    }
    int dv[4];
#pragma unroll
    for (int j = 0; j < 4; ++j) {
        int i = j * 512 + t;
        if (i < chcnt) {
            dv[j] = dst[base + i];
            __hip_atomic_fetch_add(&hist[dv[j] >> BSH], 1,
                                   __ATOMIC_RELAXED, __HIP_MEMORY_SCOPE_WORKGROUP);
        } else dv[j] = -1;
    }
    __syncthreads();
    // local hist scan (2 bins/thread)
    int c0 = (i0 < NB) ? hist[i0] : 0;
    int c1 = (i1 < NB) ? hist[i1] : 0;
    int p2 = c0 + c1, incl2 = p2;
    for (int s = 1; s < 64; s <<= 1) {
        int u = __shfl_up(incl2, s, 64);
        if (lane >= s) incl2 += u;
    }
    if (lane == 63) wsum[wid] = incl2;
    __syncthreads();
    {
        int pre = 0;
        for (int w = 0; w < wid; ++w) pre += wsum[w];
        int excl2 = pre + incl2 - p2;
        if (i0 < NB) {
            ebuf[i0] = excl2;
            cur[i0]  = 0;
            gb[i0]   = offsL[i0] + (int)mat[c * NB + i0];
        }
        if (i1 < NB) {
            ebuf[i1] = excl2 + c0;
            cur[i1]  = 0;
            gb[i1]   = offsL[i1] + (int)mat[c * NB + i1];
        }
    }
    __syncthreads();
#pragma unroll
    for (int j = 0; j < 4; ++j) {
        if (dv[j] >= 0) {
            int gi = base + j * 512 + t;
            int b  = dv[j] >> BSH;
            int p  = ebuf[b] + __hip_atomic_fetch_add(&cur[b], 1,
                            __ATOMIC_RELAXED, __HIP_MEMORY_SCOPE_WORKGROUP);
            unsigned pk = (unsigned)src[gi] | ((unsigned)(dv[j] & (BN - 1)) << 17);
            stage[p] = make_uint2(pk, __float_as_uint(e[gi]));
            bkt[p]   = (unsigned short)b;
        }
    }
    __syncthreads();
    for (int i = t; i < chcnt; i += 512) {
        int b = bkt[i];
        recs[gb[b] + (i - ebuf[b])] = stage[i];
    }
    if (c == 0) {
        for (int i = t; i <= NB; i += 512) offs_g[i] = offsL[i];
    }
}

// ---- KG: fused [in-LDS node sort + gather]. One block per 128-node bucket.
// LDS ~39.4 KB -> 4 blocks/CU; 782 blocks ~ 3.05/CU balanced.
__global__ void __launch_bounds__(512)
sort_gather_kernel(const float* __restrict__ h,
                   const unsigned short* __restrict__ h16,
                   const int* __restrict__ offs,
                   const uint2* __restrict__ recs,
                   float* __restrict__ out) {
    __shared__ unsigned key[KG_CAP];              // 18944 B
    __shared__ float    wgt[KG_CAP];              // 18944 B
    __shared__ int hist[BN], ebuf[BN], cur[BN];   // 1.5 KB
    __shared__ int wsum[2];

    const int b    = blockIdx.x;
    const int t    = threadIdx.x;
    const int lane = t & 63;
    const int wid  = t >> 6;
    const int g    = lane >> 3;        // edge group 0..7
    const int sub  = lane & 7;         // uint4 slot 0..7
    const int lo   = offs[b];
    const int cnt  = offs[b + 1] - lo;

    const uint4* __restrict__ hv = (const uint4*)h16;

#define ACC_KW(kx, wx)                                                      \
    {                                                                       \
        uint4 v = hv[((kx) & SRC_MASK) * 8 + sub];                          \
        a0 += __uint_as_float(v.x << 16) * (wx);                            \
        a1 += __uint_as_float(v.x & 0xFFFF0000u) * (wx);                    \
        a2 += __uint_as_float(v.y << 16) * (wx);                            \
        a3 += __uint_as_float(v.y & 0xFFFF0000u) * (wx);                    \
        a4 += __uint_as_float(v.z << 16) * (wx);                            \
        a5 += __uint_as_float(v.z & 0xFFFF0000u) * (wx);                    \
        a6 += __uint_as_float(v.w << 16) * (wx);                            \
        a7 += __uint_as_float(v.w & 0xFFFF0000u) * (wx);                    \
    }

    if (cnt <= KG_CAP) {
        if (t < BN) { hist[t] = 0; cur[t] = 0; }
        __syncthreads();
        // A: reg-cache recs + node histogram
        uint2 r[KG_REG];
#pragma unroll
        for (int j = 0; j < KG_REG; ++j) {
            int i = j * 512 + t;
            if (i < cnt) {
                r[j] = recs[lo + i];
                __hip_atomic_fetch_add(&hist[r[j].x >> 17], 1,
                                       __ATOMIC_RELAXED, __HIP_MEMORY_SCOPE_WORKGROUP);
            } else r[j].x = 0xFFFFFFFFu;
        }
        __syncthreads();
        // B: exclusive scan of 128 bins (2 waves, shfl + cross-wave)
        int c = 0, incl = 0;
        if (t < BN) { c = hist[t]; incl = c; }
        for (int s = 1; s < 64; s <<= 1) {
            int u = __shfl_up(incl, s, 64);
            if (lane >= s) incl += u;
        }
        if (t < BN && lane == 63) wsum[wid] = incl;
        __syncthreads();
        if (t < BN) {
            int pre = (wid == 1) ? wsum[0] : 0;
            ebuf[t] = pre + incl - c;
        }
        __syncthreads();
        // C: scatter into LDS, node-sorted
#pragma unroll
        for (int j = 0; j < KG_REG; ++j) {
            if (r[j].x != 0xFFFFFFFFu) {
                int dl = r[j].x >> 17;
                int p  = ebuf[dl] + __hip_atomic_fetch_add(&cur[dl], 1,
                                __ATOMIC_RELAXED, __HIP_MEMORY_SCOPE_WORKGROUP);
                key[p] = r[j].x;
                wgt[p] = __uint_as_float(r[j].y);
            }
        }
        __syncthreads();
        // D: gather. wave = 16 nodes; 8 groups x 8 lanes; uint4 h16 rows.
        for (int i = 0; i < 16; ++i) {
            const int ln  = wid * 16 + i;
            const int n   = (b << BSH) + ln;
            const int nlo = ebuf[ln];
            const int nhi = nlo + hist[ln];
            float a0=0.f,a1=0.f,a2=0.f,a3=0.f,a4=0.f,a5=0.f,a6=0.f,a7=0.f;
            int kk = nlo + g;
            while (kk < nhi) {
                unsigned k0 = key[kk];        float w0 = wgt[kk];
                bool m1 = kk +  8 < nhi;
                bool m2 = kk + 16 < nhi;
                bool m3 = kk + 24 < nhi;
                unsigned k1 = m1 ? key[kk +  8] : 0u;  float w1 = m1 ? wgt[kk +  8] : 0.f;
                unsigned k2 = m2 ? key[kk + 16] : 0u;  float w2 = m2 ? wgt[kk + 16] : 0.f;
                unsigned k3 = m3 ? key[kk + 24] : 0u;  float w3 = m3 ? wgt[kk + 24] : 0.f;
                ACC_KW(k0, w0); ACC_KW(k1, w1); ACC_KW(k2, w2); ACC_KW(k3, w3);
                kk += 32;
            }
            for (int m = 8; m <= 32; m <<= 1) {
                a0 += __shfl_xor(a0, m); a1 += __shfl_xor(a1, m);
                a2 += __shfl_xor(a2, m); a3 += __shfl_xor(a3, m);
                a4 += __shfl_xor(a4, m); a5 += __shfl_xor(a5, m);
                a6 += __shfl_xor(a6, m); a7 += __shfl_xor(a7, m);
            }
            if (g == 0 && n < N_NODES) {
                const float4* __restrict__ h4 = (const float4*)h;
                const int o = n * 16 + sub * 2;
                float4 p = h4[o], q = h4[o + 1];
                float4 r0, r1;
                r0.x = a0 - GAMMA * p.x; r0.y = a1 - GAMMA * p.y;
                r0.z = a2 - GAMMA * p.z; r0.w = a3 - GAMMA * p.w;
                r1.x = a4 - GAMMA * q.x; r1.y = a5 - GAMMA * q.y;
                r1.z = a6 - GAMMA * q.z; r1.w = a7 - GAMMA * q.w;
                ((float4*)out)[o]     = r0;
                ((float4*)out)[o + 1] = r1;
            }
        }
    } else {
        // overflow fallback (never expected): scan-match from global recs
        for (int i = 0; i < 16; ++i) {
            const int ln = wid * 16 + i;
            const int n  = (b << BSH) + ln;
            float a0=0.f,a1=0.f,a2=0.f,a3=0.f,a4=0.f,a5=0.f,a6=0.f,a7=0.f;
            for (int k = lo + g; k < lo + cnt; k += 8) {
                uint2 rr = recs[k];
                if ((int)(rr.x >> 17) == ln) ACC_KW(rr.x, __uint_as_float(rr.y));
            }
            for (int m = 8; m <= 32; m <<= 1) {
                a0 += __shfl_xor(a0, m); a1 += __shfl_xor(a1, m);
                a2 += __shfl_xor(a2, m); a3 += __shfl_xor(a3, m);
                a4 += __shfl_xor(a4, m); a5 += __shfl_xor(a5, m);
                a6 += __shfl_xor(a6, m); a7 += __shfl_xor(a7, m);
            }
            if (g == 0 && n < N_NODES) {
                const float4* __restrict__ h4 = (const float4*)h;
                const int o = n * 16 + sub * 2;
                float4 p = h4[o], q = h4[o + 1];
                float4 r0, r1;
                r0.x = a0 - GAMMA * p.x; r0.y = a1 - GAMMA * p.y;
                r0.z = a2 - GAMMA * p.z; r0.w = a3 - GAMMA * p.w;
                r1.x = a4 - GAMMA * q.x; r1.y = a5 - GAMMA * q.y;
                r1.z = a6 - GAMMA * q.z; r1.w = a7 - GAMMA * q.w;
                ((float4*)out)[o]     = r0;
                ((float4*)out)[o + 1] = r1;
            }
        }
    }
#undef ACC_KW
}

// ---------------- fallback atomic path (if ws too small) ----------------
__global__ void init_out_kernel(const float* __restrict__ x,
                                float* __restrict__ out,
                                int nd, int total) {
    int i = blockIdx.x * blockDim.x + threadIdx.x;
    if (i < nd)         out[i] = -GAMMA * x[i];
    else if (i < total) out[i] = 0.0f;
}

__global__ void edge_scatter_kernel(const float* __restrict__ h,
                                    const float* __restrict__ e,
                                    const int* __restrict__ src,
                                    const int* __restrict__ dst,
                                    float* __restrict__ out) {
    long long idx = (long long)blockIdx.x * blockDim.x + threadIdx.x;
    int edge = (int)(idx >> 6);
    int d    = (int)(idx & 63);
    if (edge >= N_EDGES) return;
    atomicAdd(&out[dst[edge] * D_FEAT + d], h[src[edge] * D_FEAT + d] * e[edge]);
}

// ---------------- launch ----------------
extern "C" void kernel_launch(void* const* d_in, const int* in_sizes, int n_in,
                              void* d_out, int out_size, void* d_ws, size_t ws_size,
                              hipStream_t stream) {
    const float* x   = (const float*)d_in[1];
    const int*   src = (const int*)d_in[2];
    const int*   dst = (const int*)d_in[3];
    float*       out = (float*)d_out;

    const int nd = N_NODES * D_FEAT;

    // ws: offs[NB+1] | rowsum[NB] | mat16[NC*NB] | pad->256 | recs[E] | pad->256 | h16[nd]
    size_t ints    = (size_t)(NB + 1) + NB;
    size_t mat_off = ints * 4;
    size_t rec_off = (mat_off + (size_t)NC * NB * 2 + 255) & ~(size_t)255;
    size_t h16_off = (rec_off + (size_t)N_EDGES * 8 + 255) & ~(size_t)255;
    size_t needed  = h16_off + (size_t)nd * 2;

    if (ws_size >= needed) {
        int* offs   = (int*)d_ws;
        int* rowsum = offs + NB + 1;
        unsigned short* mat  = (unsigned short*)((char*)d_ws + mat_off);
        uint2*          recs = (uint2*)((char*)d_ws + rec_off);
        unsigned short* h16  = (unsigned short*)((char*)d_ws + h16_off);

        p0_kernel<<<NC + Z_BLOCKS + CVT_BLOCKS, 256, 0, stream>>>(
            x, dst, h16, mat, out + nd);
        matscan_kernel<<<NB, 64, 0, stream>>>(mat, rowsum);
        bucket_scatter_kernel<<<NC, 512, 0, stream>>>(
            src, dst, x + nd, mat, rowsum, offs, recs);
        sort_gather_kernel<<<NB, 512, 0, stream>>>(x, h16, offs, recs, out);
    } else {
        const int total = nd + N_EDGES;
        init_out_kernel<<<(total + 255) / 256, 256, 0, stream>>>(x, out, nd, total);
        long long threads = (long long)N_EDGES * 64;
        edge_scatter_kernel<<<(int)((threads + 255) / 256), 256, 0, stream>>>(
            x, x + nd, src, dst, out);
    }
}

// Round 16
// 128.511 us; speedup vs baseline: 1.4383x; 1.0127x over previous
//
#include <hip/hip_runtime.h>

#define N_NODES 100000
#define D_FEAT  64
#define N_EDGES 3200000
#define GAMMA   0.5f

#define BSH   7                                   // 128 nodes per bucket
#define BN    (1 << BSH)                          // 128
#define NB    ((N_NODES + BN - 1) >> BSH)         // 782 buckets
#define CH    2048                                // edges per chunk
#define NC    ((N_EDGES + CH - 1) / CH)           // 1563 chunks

#define Z_BLOCKS   782                            // edge-zero blocks (4 float4/thr)
#define CVT_V4     (N_NODES * D_FEAT / 4)         // 1,600,000 float4
#define CVT_BLOCKS ((CVT_V4 + 255) / 256)         // 6250

#define KG_REG   10                               // recs cached per thread (fused)
#define KG_CAP   4736                             // bucket cap (avg 4092, +10 sigma)
#define SRC_MASK 0x1FFFFu                         // 17 bits for src

// ---- P0: [per-chunk bucket hist -> mat16] | [zero edge-out] | [h->bf16] ----
__global__ void __launch_bounds__(256)
p0_kernel(const float* __restrict__ h,
          const int* __restrict__ dst,
          unsigned short* __restrict__ h16,
          unsigned short* __restrict__ mat,
          float* __restrict__ out_edge) {
    __shared__ int hist[NB];
    const int bid = blockIdx.x;
    const int t   = threadIdx.x;
    if (bid < NC) {
        for (int i = t; i < NB; i += 256) hist[i] = 0;
        __syncthreads();
        const int base  = bid * CH;
        const int chcnt = min(N_EDGES - base, CH);      // 2048 or 1024 (4-divisible)
        const int4* dst4 = (const int4*)(dst + base);
        const int nv4 = chcnt >> 2;
#pragma unroll
        for (int j = 0; j < 2; ++j) {
            int i = j * 256 + t;
            if (i < nv4) {
                int4 d = dst4[i];
                __hip_atomic_fetch_add(&hist[d.x >> BSH], 1, __ATOMIC_RELAXED, __HIP_MEMORY_SCOPE_WORKGROUP);
                __hip_atomic_fetch_add(&hist[d.y >> BSH], 1, __ATOMIC_RELAXED, __HIP_MEMORY_SCOPE_WORKGROUP);
                __hip_atomic_fetch_add(&hist[d.z >> BSH], 1, __ATOMIC_RELAXED, __HIP_MEMORY_SCOPE_WORKGROUP);
                __hip_atomic_fetch_add(&hist[d.w >> BSH], 1, __ATOMIC_RELAXED, __HIP_MEMORY_SCOPE_WORKGROUP);
            }
        }
        __syncthreads();
        for (int i = t; i < NB; i += 256)
            mat[bid * NB + i] = (unsigned short)hist[i];
    } else if (bid < NC + Z_BLOCKS) {
        float4* oe4 = (float4*)out_edge;
        const int b2 = bid - NC;
        const float4 z = make_float4(0.f, 0.f, 0.f, 0.f);
#pragma unroll
        for (int j = 0; j < 4; ++j) {
            int i = b2 * 1024 + j * 256 + t;
            if (i < N_EDGES / 4) oe4[i] = z;
        }
    } else {
        int i = (bid - NC - Z_BLOCKS) * 256 + t;
        if (i < CVT_V4) {
            float4 v = ((const float4*)h)[i];
            ushort4 o;
            unsigned u;
            u = __float_as_uint(v.x); o.x = (unsigned short)((u + 0x7fffu + ((u >> 16) & 1u)) >> 16);
            u = __float_as_uint(v.y); o.y = (unsigned short)((u + 0x7fffu + ((u >> 16) & 1u)) >> 16);
            u = __float_as_uint(v.z); o.z = (unsigned short)((u + 0x7fffu + ((u >> 16) & 1u)) >> 16);
            u = __float_as_uint(v.w); o.w = (unsigned short)((u + 0x7fffu + ((u >> 16) & 1u)) >> 16);
            ((ushort4*)h16)[i] = o;
        }
    }
}

// ---- M1: in-place exclusive scan of each bucket row across chunks ----
__global__ void __launch_bounds__(64)
matscan_kernel(unsigned short* __restrict__ mat,
               int* __restrict__ rowsum) {
    const int b = blockIdx.x;
    const int l = threadIdx.x;
    int carry = 0;
    for (int r = 0; r < (NC + 63) / 64; ++r) {
        int c = r * 64 + l;
        int v = (c < NC) ? (int)mat[c * NB + b] : 0;
        int incl = v;
        for (int s = 1; s < 64; s <<= 1) {
            int u = __shfl_up(incl, s, 64);
            if (l >= s) incl += u;
        }
        if (c < NC) mat[c * NB + b] = (unsigned short)(carry + incl - v);
        carry += __shfl(incl, 63, 64);
    }
    if (l == 0) rowsum[b] = carry;
}

// ---- K1: chunk sort + scatter, zero global atomics (positions from mat).
// pos-trick: pos[b] starts at ebuf[b], fetch_add gives stage slot directly;
// diff[b] = gb[b]-ebuf[b] so burst addr = diff[b]+i.
__global__ void __launch_bounds__(512)
bucket_scatter_kernel(const int* __restrict__ src,
                      const int* __restrict__ dst,
                      const float* __restrict__ e,
                      const unsigned short* __restrict__ mat,
                      const int* __restrict__ rowsum,
                      int* __restrict__ offs_g,
                      uint2* __restrict__ recs) {
    __shared__ uint2          stage[CH];          // 16 KB
    __shared__ unsigned short bkt[CH];            // 4 KB
    __shared__ int hist[NB], ebuf[NB], pos[NB], diff[NB];  // 12.5 KB
    __shared__ int offsL[NB + 1];                 // 3.1 KB
    __shared__ int wsum[8];

    const int t    = threadIdx.x;
    const int lane = t & 63;
    const int wid  = t >> 6;
    const int c    = blockIdx.x;
    const int base = c * CH;
    const int chcnt = min(N_EDGES - base, CH);
    const int i0 = 2 * t, i1 = 2 * t + 1;

    for (int i = t; i < NB; i += 512) hist[i] = 0;
    // global offs scan from rowsum (2 bins/thread, shfl two-level)
    int a  = (i0 < NB) ? rowsum[i0] : 0;
    int d1 = (i1 < NB) ? rowsum[i1] : 0;
    int pair = a + d1, incl = pair;
    for (int s = 1; s < 64; s <<= 1) {
        int u = __shfl_up(incl, s, 64);
        if (lane >= s) incl += u;
    }
    if (lane == 63) wsum[wid] = incl;
    __syncthreads();
    {
        int pre = 0;
        for (int w = 0; w < wid; ++w) pre += wsum[w];
        int excl = pre + incl - pair;
        if (i0 < NB) offsL[i0] = excl;
        if (i1 < NB) offsL[i1] = excl + a;
        if (t == 511) offsL[NB] = pre + incl;     // == N_EDGES
    }
    int dv[4];
#pragma unroll
    for (int j = 0; j < 4; ++j) {
        int i = j * 512 + t;
        if (i < chcnt) {
            dv[j] = dst[base + i];
            __hip_atomic_fetch_add(&hist[dv[j] >> BSH], 1,
                                   __ATOMIC_RELAXED, __HIP_MEMORY_SCOPE_WORKGROUP);
        } else dv[j] = -1;
    }
    __syncthreads();
    // local hist scan (2 bins/thread)
    int c0 = (i0 < NB) ? hist[i0] : 0;
    int c1 = (i1 < NB) ? hist[i1] : 0;
    int p2 = c0 + c1, incl2 = p2;
    for (int s = 1; s < 64; s <<= 1) {
        int u = __shfl_up(incl2, s, 64);
        if (lane >= s) incl2 += u;
    }
    if (lane == 63) wsum[wid] = incl2;
    __syncthreads();
    {
        int pre = 0;
        for (int w = 0; w < wid; ++w) pre += wsum[w];
        int excl2 = pre + incl2 - p2;
        if (i0 < NB) {
            ebuf[i0] = excl2;
            pos[i0]  = excl2;
            diff[i0] = offsL[i0] + (int)mat[c * NB + i0] - excl2;
        }
        if (i1 < NB) {
            ebuf[i1] = excl2 + c0;
            pos[i1]  = excl2 + c0;
            diff[i1] = offsL[i1] + (int)mat[c * NB + i1] - (excl2 + c0);
        }
    }
    __syncthreads();
#pragma unroll
    for (int j = 0; j < 4; ++j) {
        if (dv[j] >= 0) {
            int gi = base + j * 512 + t;
            int b  = dv[j] >> BSH;
            int p  = __hip_atomic_fetch_add(&pos[b], 1,
                            __ATOMIC_RELAXED, __HIP_MEMORY_SCOPE_WORKGROUP);
            unsigned pk = (unsigned)src[gi] | ((unsigned)(dv[j] & (BN - 1)) << 17);
            stage[p] = make_uint2(pk, __float_as_uint(e[gi]));
            bkt[p]   = (unsigned short)b;
        }
    }
    __syncthreads();
    for (int i = t; i < chcnt; i += 512) {
        recs[diff[bkt[i]] + i] = stage[i];
    }
    if (c == 0) {
        for (int i = t; i <= NB; i += 512) offs_g[i] = offsL[i];
    }
}

// ---- KG: fused [in-LDS node sort + gather]. One block per 128-node bucket.
// kw packed uint2 (one ds_read_b64 broadcast per rec); pos-trick scatter.
__global__ void __launch_bounds__(512)
sort_gather_kernel(const float* __restrict__ h,
                   const unsigned short* __restrict__ h16,
                   const int* __restrict__ offs,
                   const uint2* __restrict__ recs,
                   float* __restrict__ out) {
    __shared__ uint2 kw[KG_CAP];                  // 37888 B
    __shared__ int hist[BN], ebuf[BN], pos[BN];   // 1.5 KB
    __shared__ int wsum[2];

    const int b    = blockIdx.x;
    const int t    = threadIdx.x;
    const int lane = t & 63;
    const int wid  = t >> 6;
    const int g    = lane >> 3;        // edge group 0..7
    const int sub  = lane & 7;         // uint4 slot 0..7
    const int lo   = offs[b];
    const int cnt  = offs[b + 1] - lo;

    const uint4* __restrict__ hv = (const uint4*)h16;

#define ACC_KW(kx, wx)                                                      \
    {                                                                       \
        uint4 v = hv[((kx) & SRC_MASK) * 8 + sub];                          \
        a0 += __uint_as_float(v.x << 16) * (wx);                            \
        a1 += __uint_as_float(v.x & 0xFFFF0000u) * (wx);                    \
        a2 += __uint_as_float(v.y << 16) * (wx);                            \
        a3 += __uint_as_float(v.y & 0xFFFF0000u) * (wx);                    \
        a4 += __uint_as_float(v.z << 16) * (wx);                            \
        a5 += __uint_as_float(v.z & 0xFFFF0000u) * (wx);                    \
        a6 += __uint_as_float(v.w << 16) * (wx);                            \
        a7 += __uint_as_float(v.w & 0xFFFF0000u) * (wx);                    \
    }

    if (cnt <= KG_CAP) {
        if (t < BN) hist[t] = 0;
        __syncthreads();
        // A: reg-cache recs + node histogram
        uint2 r[KG_REG];
#pragma unroll
        for (int j = 0; j < KG_REG; ++j) {
            int i = j * 512 + t;
            if (i < cnt) {
                r[j] = recs[lo + i];
                __hip_atomic_fetch_add(&hist[r[j].x >> 17], 1,
                                       __ATOMIC_RELAXED, __HIP_MEMORY_SCOPE_WORKGROUP);
            } else r[j].x = 0xFFFFFFFFu;
        }
        __syncthreads();
        // B: exclusive scan of 128 bins (2 waves, shfl + cross-wave)
        int c = 0, incl = 0;
        if (t < BN) { c = hist[t]; incl = c; }
        for (int s = 1; s < 64; s <<= 1) {
            int u = __shfl_up(incl, s, 64);
            if (lane >= s) incl += u;
        }
        if (t < BN && lane == 63) wsum[wid] = incl;
        __syncthreads();
        if (t < BN) {
            int pre = (wid == 1) ? wsum[0] : 0;
            int exc = pre + incl - c;
            ebuf[t] = exc;
            pos[t]  = exc;
        }
        __syncthreads();
        // C: scatter into LDS, node-sorted (pos-trick)
#pragma unroll
        for (int j = 0; j < KG_REG; ++j) {
            if (r[j].x != 0xFFFFFFFFu) {
                int dl = r[j].x >> 17;
                int p  = __hip_atomic_fetch_add(&pos[dl], 1,
                                __ATOMIC_RELAXED, __HIP_MEMORY_SCOPE_WORKGROUP);
                kw[p] = r[j];
            }
        }
        __syncthreads();
        // D: gather. wave = 16 nodes; 8 groups x 8 lanes; uint4 h16 rows.
        // pos[ln] now holds the node's END offset.
        for (int i = 0; i < 16; ++i) {
            const int ln  = wid * 16 + i;
            const int n   = (b << BSH) + ln;
            const int nlo = ebuf[ln];
            const int nhi = pos[ln];
            float a0=0.f,a1=0.f,a2=0.f,a3=0.f,a4=0.f,a5=0.f,a6=0.f,a7=0.f;
            int kk = nlo + g;
            while (kk < nhi) {
                uint2 q0 = kw[kk];
                bool m1 = kk +  8 < nhi;
                bool m2 = kk + 16 < nhi;
                bool m3 = kk + 24 < nhi;
                uint2 q1 = m1 ? kw[kk +  8] : make_uint2(0u, 0u);
                uint2 q2 = m2 ? kw[kk + 16] : make_uint2(0u, 0u);
                uint2 q3 = m3 ? kw[kk + 24] : make_uint2(0u, 0u);
                ACC_KW(q0.x, __uint_as_float(q0.y));
                ACC_KW(q1.x, __uint_as_float(q1.y));
                ACC_KW(q2.x, __uint_as_float(q2.y));
                ACC_KW(q3.x, __uint_as_float(q3.y));
                kk += 32;
            }
            for (int m = 8; m <= 32; m <<= 1) {
                a0 += __shfl_xor(a0, m); a1 += __shfl_xor(a1, m);
                a2 += __shfl_xor(a2, m); a3 += __shfl_xor(a3, m);
                a4 += __shfl_xor(a4, m); a5 += __shfl_xor(a5, m);
                a6 += __shfl_xor(a6, m); a7 += __shfl_xor(a7, m);
            }
            if (g == 0 && n < N_NODES) {
                const float4* __restrict__ h4 = (const float4*)h;
                const int o = n * 16 + sub * 2;
                float4 p = h4[o], q = h4[o + 1];
                float4 r0, r1;
                r0.x = a0 - GAMMA * p.x; r0.y = a1 - GAMMA * p.y;
                r0.z = a2 - GAMMA * p.z; r0.w = a3 - GAMMA * p.w;
                r1.x = a4 - GAMMA * q.x; r1.y = a5 - GAMMA * q.y;
                r1.z = a6 - GAMMA * q.z; r1.w = a7 - GAMMA * q.w;
                ((float4*)out)[o]     = r0;
                ((float4*)out)[o + 1] = r1;
            }
        }
    } else {
        // overflow fallback (never expected): scan-match from global recs
        for (int i = 0; i < 16; ++i) {
            const int ln = wid * 16 + i;
            const int n  = (b << BSH) + ln;
            float a0=0.f,a1=0.f,a2=0.f,a3=0.f,a4=0.f,a5=0.f,a6=0.f,a7=0.f;
            for (int k = lo + g; k < lo + cnt; k += 8) {
                uint2 rr = recs[k];
                if ((int)(rr.x >> 17) == ln) ACC_KW(rr.x, __uint_as_float(rr.y));
            }
            for (int m = 8; m <= 32; m <<= 1) {
                a0 += __shfl_xor(a0, m); a1 += __shfl_xor(a1, m);
                a2 += __shfl_xor(a2, m); a3 += __shfl_xor(a3, m);
                a4 += __shfl_xor(a4, m); a5 += __shfl_xor(a5, m);
                a6 += __shfl_xor(a6, m); a7 += __shfl_xor(a7, m);
            }
            if (g == 0 && n < N_NODES) {
                const float4* __restrict__ h4 = (const float4*)h;
                const int o = n * 16 + sub * 2;
                float4 p = h4[o], q = h4[o + 1];
                float4 r0, r1;
                r0.x = a0 - GAMMA * p.x; r0.y = a1 - GAMMA * p.y;
                r0.z = a2 - GAMMA * p.z; r0.w = a3 - GAMMA * p.w;
                r1.x = a4 - GAMMA * q.x; r1.y = a5 - GAMMA * q.y;
                r1.z = a6 - GAMMA * q.z; r1.w = a7 - GAMMA * q.w;
                ((float4*)out)[o]     = r0;
                ((float4*)out)[o + 1] = r1;
            }
        }
    }
#undef ACC_KW
}

// ---------------- fallback atomic path (if ws too small) ----------------
__global__ void init_out_kernel(const float* __restrict__ x,
                                float* __restrict__ out,
                                int nd, int total) {
    int i = blockIdx.x * blockDim.x + threadIdx.x;
    if (i < nd)         out[i] = -GAMMA * x[i];
    else if (i < total) out[i] = 0.0f;
}

__global__ void edge_scatter_kernel(const float* __restrict__ h,
                                    const float* __restrict__ e,
                                    const int* __restrict__ src,
                                    const int* __restrict__ dst,
                                    float* __restrict__ out) {
    long long idx = (long long)blockIdx.x * blockDim.x + threadIdx.x;
    int edge = (int)(idx >> 6);
    int d    = (int)(idx & 63);
    if (edge >= N_EDGES) return;
    atomicAdd(&out[dst[edge] * D_FEAT + d], h[src[edge] * D_FEAT + d] * e[edge]);
}

// ---------------- launch ----------------
extern "C" void kernel_launch(void* const* d_in, const int* in_sizes, int n_in,
                              void* d_out, int out_size, void* d_ws, size_t ws_size,
                              hipStream_t stream) {
    const float* x   = (const float*)d_in[1];
    const int*   src = (const int*)d_in[2];
    const int*   dst = (const int*)d_in[3];
    float*       out = (float*)d_out;

    const int nd = N_NODES * D_FEAT;

    // ws: offs[NB+1] | rowsum[NB] | mat16[NC*NB] | pad->256 | recs[E] | pad->256 | h16[nd]
    size_t ints    = (size_t)(NB + 1) + NB;
    size_t mat_off = ints * 4;
    size_t rec_off = (mat_off + (size_t)NC * NB * 2 + 255) & ~(size_t)255;
    size_t h16_off = (rec_off + (size_t)N_EDGES * 8 + 255) & ~(size_t)255;
    size_t needed  = h16_off + (size_t)nd * 2;

    if (ws_size >= needed) {
        int* offs   = (int*)d_ws;
        int* rowsum = offs + NB + 1;
        unsigned short* mat  = (unsigned short*)((char*)d_ws + mat_off);
        uint2*          recs = (uint2*)((char*)d_ws + rec_off);
        unsigned short* h16  = (unsigned short*)((char*)d_ws + h16_off);

        p0_kernel<<<NC + Z_BLOCKS + CVT_BLOCKS, 256, 0, stream>>>(
            x, dst, h16, mat, out + nd);
        matscan_kernel<<<NB, 64, 0, stream>>>(mat, rowsum);
        bucket_scatter_kernel<<<NC, 512, 0, stream>>>(
            src, dst, x + nd, mat, rowsum, offs, recs);
        sort_gather_kernel<<<NB, 512, 0, stream>>>(x, h16, offs, recs, out);
    } else {
        const int total = nd + N_EDGES;
        init_out_kernel<<<(total + 255) / 256, 256, 0, stream>>>(x, out, nd, total);
        long long threads = (long long)N_EDGES * 64;
        edge_scatter_kernel<<<(int)((threads + 255) / 256), 256, 0, stream>>>(
            x, x + nd, src, dst, out);
    }
}